// Round 1
// baseline (156375.635 us; speedup 1.0000x reference)
//
#include <hip/hip_runtime.h>
#include <math.h>

// ============================================================================
// KNet RNN (KalmanNet) — persistent-kernel fp32 implementation, round 0.
// T=256 sequential steps; one persistent kernel, 8 grid barriers per step.
// Grid: 256 WGs x 512 threads (1 WG/CU -> all co-resident; hand-rolled
// epoch barrier, per-epoch counters zeroed by init kernel).
// ============================================================================

#define NWG 256
#define NTH 512
#define NT  (NWG*NTH)
#define TT  256
#define D2  18000
#define NEPOCH 2080

// int region of ws (in ints)
#define OFF_ATOP (NEPOCH*8)
#define OFF_GO   (NEPOCH*9)
#define INT_TOTAL 18944          // padded; *4 = 75776 bytes (256B aligned)

// float region offsets (floats)
#define F_HQ   0                 // [2][3600] double-buffered
#define F_HS   7200              // [2][3600]
#define F_HSIG 14400             // [3600]
#define F_XP   18000             // [240] x_post
#define F_DY   18240             // [240] obs - x_prior  (= obs_innov_diff)
#define F_FWD  18480             // [240] x_post - x_post_prev (== update diff)
#define F_OBSD 18720             // [240] obs - y_prev
#define F_OUT5 18960             // [16*75]
#define F_OUT6 20160             // [16*75]
#define F_OUT7 21360             // [16*150]
#define F_OSIG 23760             // [3600]
#define F_OUT1 27360             // [3600]
#define F_OUT2 30960             // [3600]
#define F_OUT3 34560             // [3600]
#define F_VT   38160             // [450*16] transposed [osig|hS] for W2a GEMV
#define F_HID2 45360             // [16*18000]

struct KArgs {
  const float *y,*x0,*hQ0,*hSig0,*hS0;
  const float *WihQ,*WhhQ,*bihQ,*bhhQ;
  const float *WihSig,*WhhSig,*bihSig,*bhhSig;
  const float *WihS,*WhhS,*bihS,*bhhS;
  const float *W1,*b1,*W2a,*b2a,*W2b,*b2b,*W3,*b3,*W4,*b4;
  const float *W5,*b5,*W6,*b6,*W7,*b7;
  float* out;
  int*   ib;
  float* fb;
};

__device__ __forceinline__ float sigf(float x) { return 1.0f/(1.0f + __expf(-x)); }

// Two-level epoch barrier. Per-epoch counters (no reset -> no reuse races).
// 8 groups of 32 WGs -> top counter of 8 -> go flag. Device-scope atomics
// handle cross-XCD coherence; threadfence releases/acquires data buffers.
__device__ __forceinline__ void gbar(int* ib, int e) {
  __syncthreads();
  if (threadIdx.x == 0) {
    __threadfence();
    int g = (int)(blockIdx.x >> 5);
    int prev = __hip_atomic_fetch_add(ib + (e<<3) + g, 1,
                                      __ATOMIC_ACQ_REL, __HIP_MEMORY_SCOPE_AGENT);
    if (prev == 31) {
      int pt = __hip_atomic_fetch_add(ib + OFF_ATOP + e, 1,
                                      __ATOMIC_ACQ_REL, __HIP_MEMORY_SCOPE_AGENT);
      if (pt == 7)
        __hip_atomic_store(ib + OFF_GO, e, __ATOMIC_RELEASE, __HIP_MEMORY_SCOPE_AGENT);
    }
    while (__hip_atomic_load(ib + OFF_GO, __ATOMIC_RELAXED, __HIP_MEMORY_SCOPE_AGENT) < e)
      __builtin_amdgcn_s_sleep(4);
    __threadfence();
  }
  __syncthreads();
}

__global__ void knet_init(KArgs a) {
  int gt = blockIdx.x*blockDim.x + threadIdx.x;
  int nt = gridDim.x*blockDim.x;
  for (int i = gt; i < INT_TOTAL; i += nt) a.ib[i] = (i == OFF_GO) ? -1 : 0;
  float* F = a.fb;
  for (int i = gt; i < 3600; i += nt) {
    F[F_HQ   + i] = a.hQ0[i];
    F[F_HS   + i] = a.hS0[i];
    F[F_HSIG + i] = a.hSig0[i];
  }
  for (int i = gt; i < 240; i += nt) {
    int b = i / 15, j = i - b*15;
    float xv = a.x0[i];
    float ob = a.y[b*30 + j];       // obs at t=0
    F[F_XP   + i] = xv;
    F[F_DY   + i] = ob - xv;        // obs - x_prior
    F[F_OBSD + i] = ob - xv;        // obs - y_prev (y_prev init = x0)
    F[F_FWD  + i] = 0.f;            // x0 - x0
  }
}

__global__ __launch_bounds__(NTH, 1) void knet_main(KArgs a) {
  __shared__ float smem[7200];
  const int tid  = threadIdx.x;
  const int gtid = blockIdx.x*NTH + tid;
  float* F  = a.fb;
  int*   ib = a.ib;
  int ep = 0;

  for (int t = 0; t < TT; ++t) {
    const int p = t & 1, q = p ^ 1;
    float* hQi = F + F_HQ + p*3600;  float* hQo = F + F_HQ + q*3600;
    float* hSi = F + F_HS + p*3600;  float* hSo = F + F_HS + q*3600;

    // ---- S0: out4(prev step)->hSig ; out5 ; out6 ; out7 -------------------
    for (int idx = gtid; idx < 8400; idx += NT) {
      if (idx < 3600) {
        if (t > 0) {
          int j = idx >> 4, b = idx & 15;
          float acc = a.b4[j];
          const float* w  = a.W4 + j*450;
          const float* v1 = F + F_OSIG + b*225;
          const float* v2 = F + F_OUT3 + b*225;
          #pragma unroll 4
          for (int d = 0; d < 225; ++d) acc = fmaf(w[d],     v1[d], acc);
          #pragma unroll 4
          for (int d = 0; d < 225; ++d) acc = fmaf(w[225+d], v2[d], acc);
          F[F_HSIG + b*225 + j] = fmaxf(acc, 0.f);
        }
      } else if (idx < 4800) {
        int i = idx - 3600; int j = i >> 4, b = i & 15;
        float acc = a.b5[j];
        const float* w = a.W5 + j*15;
        const float* v = F + F_FWD + b*15;
        #pragma unroll
        for (int d = 0; d < 15; ++d) acc = fmaf(w[d], v[d], acc);
        F[F_OUT5 + b*75 + j] = fmaxf(acc, 0.f);
      } else if (idx < 6000) {
        int i = idx - 4800; int j = i >> 4, b = i & 15;
        float acc = a.b6[j];
        const float* w = a.W6 + j*15;
        const float* v = F + F_FWD + b*15;      // update diff == evol diff
        #pragma unroll
        for (int d = 0; d < 15; ++d) acc = fmaf(w[d], v[d], acc);
        F[F_OUT6 + b*75 + j] = fmaxf(acc, 0.f);
      } else {
        int i = idx - 6000; int j = i >> 4, b = i & 15;
        float acc = a.b7[j];
        const float* w  = a.W7 + j*30;
        const float* vo = F + F_OBSD + b*15;
        const float* vd = F + F_DY   + b*15;
        #pragma unroll
        for (int d = 0; d < 15; ++d) acc = fmaf(w[d],    vo[d], acc);
        #pragma unroll
        for (int d = 0; d < 15; ++d) acc = fmaf(w[15+d], vd[d], acc);
        F[F_OUT7 + b*150 + j] = fmaxf(acc, 0.f);
      }
    }
    gbar(ib, ep); ++ep;

    // ---- S1: hQ GRU (x=out5 K=75, h=hQ) -----------------------------------
    for (int idx = gtid; idx < 3600; idx += NT) {
      int j = idx >> 4, b = idx & 15;
      float ir = a.bihQ[j], iz = a.bihQ[225+j], inn = a.bihQ[450+j];
      const float* x  = F + F_OUT5 + b*75;
      const float* w0 = a.WihQ + j*75;
      const float* w1 = a.WihQ + (225+j)*75;
      const float* w2 = a.WihQ + (450+j)*75;
      #pragma unroll 3
      for (int d = 0; d < 75; ++d) {
        float xv = x[d];
        ir = fmaf(w0[d], xv, ir); iz = fmaf(w1[d], xv, iz); inn = fmaf(w2[d], xv, inn);
      }
      float hr = a.bhhQ[j], hz = a.bhhQ[225+j], hn = a.bhhQ[450+j];
      const float* h  = hQi + b*225;
      const float* u0 = a.WhhQ + j*225;
      const float* u1 = a.WhhQ + (225+j)*225;
      const float* u2 = a.WhhQ + (450+j)*225;
      #pragma unroll 3
      for (int d = 0; d < 225; ++d) {
        float hv = h[d];
        hr = fmaf(u0[d], hv, hr); hz = fmaf(u1[d], hv, hz); hn = fmaf(u2[d], hv, hn);
      }
      float r = sigf(ir + hr), z = sigf(iz + hz);
      float n = tanhf(fmaf(r, hn, inn));
      hQo[b*225 + j] = (1.f - z)*n + z*h[j];
    }
    gbar(ib, ep); ++ep;

    // ---- S2: out_sigma GRU (x=[hQ,out6] K=300, h=hSig) -> osig + vt -------
    for (int idx = gtid; idx < 3600; idx += NT) {
      int j = idx >> 4, b = idx & 15;
      float ir = a.bihSig[j], iz = a.bihSig[225+j], inn = a.bihSig[450+j];
      const float* x1 = hQo + b*225;
      const float* x2 = F + F_OUT6 + b*75;
      const float* w0 = a.WihSig + j*300;
      const float* w1 = a.WihSig + (225+j)*300;
      const float* w2 = a.WihSig + (450+j)*300;
      #pragma unroll 3
      for (int d = 0; d < 225; ++d) {
        float xv = x1[d];
        ir = fmaf(w0[d], xv, ir); iz = fmaf(w1[d], xv, iz); inn = fmaf(w2[d], xv, inn);
      }
      #pragma unroll 3
      for (int d = 0; d < 75; ++d) {
        float xv = x2[d];
        ir = fmaf(w0[225+d], xv, ir); iz = fmaf(w1[225+d], xv, iz); inn = fmaf(w2[225+d], xv, inn);
      }
      float hr = a.bhhSig[j], hz = a.bhhSig[225+j], hn = a.bhhSig[450+j];
      const float* h  = F + F_HSIG + b*225;
      const float* u0 = a.WhhSig + j*225;
      const float* u1 = a.WhhSig + (225+j)*225;
      const float* u2 = a.WhhSig + (450+j)*225;
      #pragma unroll 3
      for (int d = 0; d < 225; ++d) {
        float hv = h[d];
        hr = fmaf(u0[d], hv, hr); hz = fmaf(u1[d], hv, hz); hn = fmaf(u2[d], hv, hn);
      }
      float r = sigf(ir + hr), z = sigf(iz + hz);
      float n = tanhf(fmaf(r, hn, inn));
      float val = (1.f - z)*n + z*h[j];
      F[F_OSIG + b*225 + j] = val;
      F[F_VT + j*16 + b]    = val;     // transposed for W2a GEMV
    }
    gbar(ib, ep); ++ep;

    // ---- S3: out1 = relu(osig @ W1^T + b1); seed out2 with b2b ------------
    for (int idx = gtid; idx < 7200; idx += NT) {
      if (idx < 3600) {
        int j = idx >> 4, b = idx & 15;
        float acc = a.b1[j];
        const float* w = a.W1 + j*225;
        const float* v = F + F_OSIG + b*225;
        #pragma unroll 4
        for (int d = 0; d < 225; ++d) acc = fmaf(w[d], v[d], acc);
        F[F_OUT1 + b*225 + j] = fmaxf(acc, 0.f);
      } else {
        int i = idx - 3600; int j = i >> 4, b = i & 15;
        F[F_OUT2 + b*225 + j] = a.b2b[j];   // bias seed for split-K atomics
      }
    }
    gbar(ib, ep); ++ep;

    // ---- S4: hS GRU (x=[out1,out7] K=375, h=hS) -> hSo + vt ---------------
    for (int idx = gtid; idx < 3600; idx += NT) {
      int j = idx >> 4, b = idx & 15;
      float ir = a.bihS[j], iz = a.bihS[225+j], inn = a.bihS[450+j];
      const float* x1 = F + F_OUT1 + b*225;
      const float* x2 = F + F_OUT7 + b*150;
      const float* w0 = a.WihS + j*375;
      const float* w1 = a.WihS + (225+j)*375;
      const float* w2 = a.WihS + (450+j)*375;
      #pragma unroll 3
      for (int d = 0; d < 225; ++d) {
        float xv = x1[d];
        ir = fmaf(w0[d], xv, ir); iz = fmaf(w1[d], xv, iz); inn = fmaf(w2[d], xv, inn);
      }
      #pragma unroll 3
      for (int d = 0; d < 150; ++d) {
        float xv = x2[d];
        ir = fmaf(w0[225+d], xv, ir); iz = fmaf(w1[225+d], xv, iz); inn = fmaf(w2[225+d], xv, inn);
      }
      float hr = a.bhhS[j], hz = a.bhhS[225+j], hn = a.bhhS[450+j];
      const float* h  = hSi + b*225;
      const float* u0 = a.WhhS + j*225;
      const float* u1 = a.WhhS + (225+j)*225;
      const float* u2 = a.WhhS + (450+j)*225;
      #pragma unroll 3
      for (int d = 0; d < 225; ++d) {
        float hv = h[d];
        hr = fmaf(u0[d], hv, hr); hz = fmaf(u1[d], hv, hz); hn = fmaf(u2[d], hv, hn);
      }
      float r = sigf(ir + hr), z = sigf(iz + hz);
      float n = tanhf(fmaf(r, hn, inn));
      float val = (1.f - z)*n + z*h[j];
      hSo[b*225 + j]           = val;
      F[F_VT + (225+j)*16 + b] = val;
    }
    gbar(ib, ep); ++ep;

    // ---- S5: hid2 = relu(W2a @ [osig|hS] + b2a) — the big GEMV ------------
    // vt staged in LDS ([d][b], one 64B line per wave-load); each thread
    // computes 2-3 outputs (same b) sharing each v read across 3 FMAs.
    for (int i = tid; i < 7200; i += NTH) smem[i] = F[F_VT + i];
    __syncthreads();
    {
      int b = gtid & 15, o0 = gtid >> 4;        // o0 < 8192
      int o1 = o0 + 8192, o2 = o0 + 16384;
      bool has2 = (o2 < D2);
      const float* w0 = a.W2a + o0*450;
      const float* w1 = a.W2a + o1*450;
      const float* w2 = a.W2a + (has2 ? o2 : o0)*450;
      float ac0 = a.b2a[o0], ac1 = a.b2a[o1], ac2 = has2 ? a.b2a[o2] : 0.f;
      #pragma unroll 2
      for (int d = 0; d < 450; ++d) {
        float vv = smem[d*16 + b];
        ac0 = fmaf(w0[d], vv, ac0);
        ac1 = fmaf(w1[d], vv, ac1);
        ac2 = fmaf(w2[d], vv, ac2);
      }
      float* h2 = F + F_HID2 + b*D2;
      h2[o0] = fmaxf(ac0, 0.f);
      h2[o1] = fmaxf(ac1, 0.f);
      if (has2) h2[o2] = fmaxf(ac2, 0.f);
    }
    gbar(ib, ep); ++ep;

    // ---- S6: out2 += W2b-chunk @ hid2-chunk (split-K, atomics) ------------
    {
      int kc0 = blockIdx.x * 71;
      int kn  = D2 - kc0; if (kn > 71) kn = 71;   // <=0 for last 2 WGs
      if (kn > 0) {
        for (int i = tid; i < 16*71; i += NTH) {
          int b = i / 71, k = i - b*71;
          if (k < kn) smem[b*73 + k] = F[F_HID2 + b*D2 + kc0 + k];
        }
      }
      __syncthreads();
      if (kn > 0) {
        for (int idx = tid; idx < 3600; idx += NTH) {
          int j = idx >> 4, b = idx & 15;
          const float* w  = a.W2b + j*D2 + kc0;
          const float* hh = smem + b*73;
          float acc = 0.f;
          for (int k = 0; k < kn; ++k) acc = fmaf(w[k], hh[k], acc);
          atomicAdd(&F[F_OUT2 + b*225 + j], acc);
        }
      }
    }
    gbar(ib, ep); ++ep;

    // ---- S7: out3 = relu([hS,out2]@W3^T+b3) ; x update ; next diffs -------
    for (int idx = gtid; idx < 3840; idx += NT) {
      if (idx < 3600) {
        int j = idx >> 4, b = idx & 15;
        float acc = a.b3[j];
        const float* w  = a.W3 + j*450;
        const float* v1 = hSo + b*225;
        const float* v2 = F + F_OUT2 + b*225;
        #pragma unroll 4
        for (int d = 0; d < 225; ++d) acc = fmaf(w[d],     v1[d], acc);
        #pragma unroll 4
        for (int d = 0; d < 225; ++d) acc = fmaf(w[225+d], v2[d], acc);
        F[F_OUT3 + b*225 + j] = fmaxf(acc, 0.f);
      } else {
        int i = idx - 3600; int b = i / 15, jj = i - b*15;
        float xold = F[F_XP + i];
        float kg   = F[F_OUT2 + b*225 + jj];     // KG[:,0,:] = out2[:, :15]
        float xnew = fmaf(kg, F[F_DY + i], xold);
        a.out[t*240 + i] = xnew;
        F[F_XP + i] = xnew;
        if (t + 1 < TT) {
          float obs1 = a.y[(t+1)*480 + b*30 + jj];
          float obs0 = a.y[t*480     + b*30 + jj];
          F[F_DY   + i] = obs1 - xnew;   // obs(t+1) - x_prior(t+1)
          F[F_OBSD + i] = obs1 - obs0;   // obs(t+1) - y_prev(t+1)
          F[F_FWD  + i] = xnew - xold;   // x_post - x_post_prev
        }
      }
    }
    gbar(ib, ep); ++ep;   // 8th barrier: protects osig/out3 for next S0 out4
  }
}

extern "C" void kernel_launch(void* const* d_in, const int* in_sizes, int n_in,
                              void* d_out, int out_size, void* d_ws, size_t ws_size,
                              hipStream_t stream) {
  (void)in_sizes; (void)n_in; (void)out_size; (void)ws_size;
  KArgs a;
  int k = 0;
  a.y      = (const float*)d_in[k++];
  a.x0     = (const float*)d_in[k++];
  a.hQ0    = (const float*)d_in[k++];
  a.hSig0  = (const float*)d_in[k++];
  a.hS0    = (const float*)d_in[k++];
  a.WihQ   = (const float*)d_in[k++];
  a.WhhQ   = (const float*)d_in[k++];
  a.bihQ   = (const float*)d_in[k++];
  a.bhhQ   = (const float*)d_in[k++];
  a.WihSig = (const float*)d_in[k++];
  a.WhhSig = (const float*)d_in[k++];
  a.bihSig = (const float*)d_in[k++];
  a.bhhSig = (const float*)d_in[k++];
  a.WihS   = (const float*)d_in[k++];
  a.WhhS   = (const float*)d_in[k++];
  a.bihS   = (const float*)d_in[k++];
  a.bhhS   = (const float*)d_in[k++];
  a.W1  = (const float*)d_in[k++];  a.b1  = (const float*)d_in[k++];
  a.W2a = (const float*)d_in[k++];  a.b2a = (const float*)d_in[k++];
  a.W2b = (const float*)d_in[k++];  a.b2b = (const float*)d_in[k++];
  a.W3  = (const float*)d_in[k++];  a.b3  = (const float*)d_in[k++];
  a.W4  = (const float*)d_in[k++];  a.b4  = (const float*)d_in[k++];
  a.W5  = (const float*)d_in[k++];  a.b5  = (const float*)d_in[k++];
  a.W6  = (const float*)d_in[k++];  a.b6  = (const float*)d_in[k++];
  a.W7  = (const float*)d_in[k++];  a.b7  = (const float*)d_in[k++];
  a.out = (float*)d_out;
  a.ib  = (int*)d_ws;
  a.fb  = (float*)((char*)d_ws + INT_TOTAL*sizeof(int));

  hipLaunchKernelGGL(knet_init, dim3(128), dim3(256), 0, stream, a);
  hipLaunchKernelGGL(knet_main, dim3(NWG), dim3(NTH), 0, stream, a);
}

// Round 2
// 102680.151 us; speedup vs baseline: 1.5229x; 1.5229x over previous
//
#include <hip/hip_runtime.h>
#include <math.h>

// ============================================================================
// KNet RNN — persistent kernel, round 2: latency-parallel GEMVs.
// 256 WGs x 1024 threads (16 waves/CU). 7 grid barriers per step.
// Small GEMVs: 4-way k-split per wave (lane = b + 16*kc) + shuffle reduce.
// S5 (W2a 32MB): 4 rows/wave, float4 weight streams, LDS x [b][452].
// S6 (W2b 16MB): (4j, b, khalf) per wave, coalesced float4, no atomics;
// partials reduced in S7 (W3@b2b folded into precomputed c3).
// ============================================================================

#define NWG 256
#define NTH 1024
#define WPG 16
#define TT  256
#define NEPOCH 1800
#define OFF_ATOP (NEPOCH*8)
#define OFF_GO   (NEPOCH*9)
#define INT_TOTAL 16256          // *4 bytes, 16B-aligned end

// float-region offsets (in floats; all multiples of 4 -> 16B aligned)
#define F_HQ   0                 // [2][3600]
#define F_HS   7200              // [2][3600]
#define F_HSIG 14400             // [3600]
#define F_XP   18000             // [240]
#define F_DY   18240             // [240]
#define F_FWD  18480             // [240]
#define F_OBSD 18720             // [240]
#define F_OSIG 18960             // [3600]  [b][225]
#define F_OUT1 22560             // [3600]
#define F_OUT3 26160             // [3600]
#define F_VT   29760             // [16][452]  x-vector for W2a: [b][osig|hS]
#define F_P2   36992             // [2][3600]  W2b k-half partials
#define F_C3   44192             // [225]      W3[:,225:] @ b2b
#define F_HID2 44432             // [16][18000]

struct KArgs {
  const float *y,*x0,*hQ0,*hSig0,*hS0;
  const float *WihQ,*WhhQ,*bihQ,*bhhQ;
  const float *WihSig,*WhhSig,*bihSig,*bhhSig;
  const float *WihS,*WhhS,*bihS,*bhhS;
  const float *W1,*b1,*W2a,*b2a,*W2b,*b2b,*W3,*b3,*W4,*b4;
  const float *W5,*b5,*W6,*b6,*W7,*b7;
  float* out;
  int*   ib;
  float* fb;
};

__device__ __forceinline__ float sigf(float x) { return 1.0f/(1.0f + __expf(-x)); }

__device__ __forceinline__ float redkc(float v) {   // reduce over kc (lanes ^16, ^32)
  v += __shfl_xor(v, 16, 64);
  v += __shfl_xor(v, 32, 64);
  return v;
}
__device__ __forceinline__ float red64(float v) {
  v += __shfl_xor(v, 1, 64);  v += __shfl_xor(v, 2, 64);
  v += __shfl_xor(v, 4, 64);  v += __shfl_xor(v, 8, 64);
  v += __shfl_xor(v, 16, 64); v += __shfl_xor(v, 32, 64);
  return v;
}

// Two-level epoch barrier: per-epoch counters (init-zeroed), 8 groups of 32.
__device__ __forceinline__ void gbar(int* ib, int e) {
  __syncthreads();
  if (threadIdx.x == 0) {
    __threadfence();
    int g = (int)(blockIdx.x >> 5);
    int prev = __hip_atomic_fetch_add(ib + (e<<3) + g, 1,
                                      __ATOMIC_ACQ_REL, __HIP_MEMORY_SCOPE_AGENT);
    if (prev == 31) {
      int pt = __hip_atomic_fetch_add(ib + OFF_ATOP + e, 1,
                                      __ATOMIC_ACQ_REL, __HIP_MEMORY_SCOPE_AGENT);
      if (pt == 7)
        __hip_atomic_store(ib + OFF_GO, e, __ATOMIC_RELEASE, __HIP_MEMORY_SCOPE_AGENT);
    }
    while (__hip_atomic_load(ib + OFF_GO, __ATOMIC_RELAXED, __HIP_MEMORY_SCOPE_AGENT) < e)
      __builtin_amdgcn_s_sleep(2);
    __threadfence();
  }
  __syncthreads();
}

__global__ void knet_init(KArgs a) {
  int gt = blockIdx.x*blockDim.x + threadIdx.x;
  int nt = gridDim.x*blockDim.x;
  for (int i = gt; i < INT_TOTAL; i += nt) a.ib[i] = (i == OFF_GO) ? -1 : 0;
  float* F = a.fb;
  for (int i = gt; i < 3600; i += nt) {
    F[F_HQ   + i] = a.hQ0[i];
    F[F_HS   + i] = a.hS0[i];
    F[F_HSIG + i] = a.hSig0[i];
  }
  for (int i = gt; i < 240; i += nt) {
    int b = i / 15, j = i - b*15;
    float xv = a.x0[i];
    float ob = a.y[b*30 + j];
    F[F_XP   + i] = xv;
    F[F_DY   + i] = ob - xv;
    F[F_OBSD + i] = ob - xv;
    F[F_FWD  + i] = 0.f;
  }
  for (int j = gt; j < 225; j += nt) {        // c3[j] = W3[j,225:] @ b2b
    float acc = 0.f;
    const float* w = a.W3 + j*450 + 225;
    for (int d = 0; d < 225; ++d) acc += w[d]*a.b2b[d];
    F[F_C3 + j] = acc;
  }
}

__global__ __launch_bounds__(NTH) void knet_main(KArgs a) {
  __shared__ float smem[7232];
  const int tid  = threadIdx.x;
  const int widx = tid >> 6;
  const int l    = tid & 63;
  const int b    = l & 15;
  const int kc   = l >> 4;
  const int wv   = (int)blockIdx.x * WPG + widx;
  float* F  = a.fb;
  int*   ib = a.ib;
  int ep = 0;

  const int d0_57 = kc*57, d1_57 = (kc==3) ? 225 : kc*57 + 57;
  const int d0_19 = kc*19, d1_19 = (kc==3) ? 75  : kc*19 + 19;
  const int d0_38 = kc*38, d1_38 = (kc==3) ? 150 : kc*38 + 38;

  for (int t = 0; t < TT; ++t) {
    const int p = t & 1, q = p ^ 1;
    float* hQi = F + F_HQ + p*3600;  float* hQo = F + F_HQ + q*3600;
    float* hSi = F + F_HS + p*3600;  float* hSo = F + F_HS + q*3600;

    // ==== S01: hSig(out4 finish) [waves 0..224] + hQ GRU [waves 225..449] ==
    if (blockIdx.x >= 14 && blockIdx.x < 29) {       // out5 -> LDS for hQ WGs
      for (int i = tid; i < 1200; i += NTH) {
        int bb = i/75, j5 = i - bb*75;
        float acc = a.b5[j5];
        const float* w = a.W5 + j5*15;
        const float* v = F + F_FWD + bb*15;
        #pragma unroll
        for (int d = 0; d < 15; ++d) acc = fmaf(w[d], v[d], acc);
        smem[i] = fmaxf(acc, 0.f);
      }
      __syncthreads();
    }
    if (wv < 225) {                    // hSig = relu(W4 @ [osig,out3] + b4)
      if (t > 0) {
        int j = wv;
        const float* w  = a.W4 + j*450;
        const float* v1 = F + F_OSIG + b*225;
        const float* v2 = F + F_OUT3 + b*225;
        float acc = 0.f;
        for (int d = d0_57; d < d1_57; ++d) acc = fmaf(w[d],     v1[d], acc);
        for (int d = d0_57; d < d1_57; ++d) acc = fmaf(w[225+d], v2[d], acc);
        acc = redkc(acc);
        if (kc == 0) F[F_HSIG + b*225 + j] = fmaxf(acc + a.b4[j], 0.f);
      }
    } else if (wv < 450) {             // hQ GRU, x = out5 (LDS)
      int j = wv - 225;
      float ir=0.f, iz=0.f, inn=0.f, hr=0.f, hz=0.f, hn=0.f;
      const float* w0 = a.WihQ + j*75;
      for (int d = d0_19; d < d1_19; ++d) {
        float xv = smem[b*75 + d];
        ir = fmaf(w0[d], xv, ir); iz = fmaf(w0[16875+d], xv, iz); inn = fmaf(w0[33750+d], xv, inn);
      }
      const float* u0 = a.WhhQ + j*225;
      const float* h  = hQi + b*225;
      for (int d = d0_57; d < d1_57; ++d) {
        float hv = h[d];
        hr = fmaf(u0[d], hv, hr); hz = fmaf(u0[50625+d], hv, hz); hn = fmaf(u0[101250+d], hv, hn);
      }
      ir = redkc(ir); iz = redkc(iz); inn = redkc(inn);
      hr = redkc(hr); hz = redkc(hz); hn = redkc(hn);
      if (kc == 0) {
        float r = sigf(ir + hr + a.bihQ[j]     + a.bhhQ[j]);
        float z = sigf(iz + hz + a.bihQ[225+j] + a.bhhQ[225+j]);
        float n = tanhf(inn + a.bihQ[450+j] + r*(hn + a.bhhQ[450+j]));
        hQo[b*225 + j] = (1.f - z)*n + z*h[j];
      }
    }
    gbar(ib, ep); ++ep;

    // ==== S2: out_sigma GRU [waves 0..224], x=[hQ,out6], h=hSig ============
    if (blockIdx.x < 15) {                          // out6 -> LDS
      for (int i = tid; i < 1200; i += NTH) {
        int bb = i/75, j6 = i - bb*75;
        float acc = a.b6[j6];
        const float* w = a.W6 + j6*15;
        const float* v = F + F_FWD + bb*15;
        #pragma unroll
        for (int d = 0; d < 15; ++d) acc = fmaf(w[d], v[d], acc);
        smem[i] = fmaxf(acc, 0.f);
      }
      __syncthreads();
    }
    if (wv < 225) {
      int j = wv;
      float ir=0.f, iz=0.f, inn=0.f, hr=0.f, hz=0.f, hn=0.f;
      const float* w0 = a.WihSig + j*300;
      const float* x1 = hQo + b*225;
      for (int d = d0_57; d < d1_57; ++d) {
        float xv = x1[d];
        ir = fmaf(w0[d], xv, ir); iz = fmaf(w0[67500+d], xv, iz); inn = fmaf(w0[135000+d], xv, inn);
      }
      for (int d = d0_19; d < d1_19; ++d) {
        float xv = smem[b*75 + d];
        ir = fmaf(w0[225+d], xv, ir); iz = fmaf(w0[67725+d], xv, iz); inn = fmaf(w0[135225+d], xv, inn);
      }
      const float* u0 = a.WhhSig + j*225;
      const float* h  = F + F_HSIG + b*225;
      for (int d = d0_57; d < d1_57; ++d) {
        float hv = h[d];
        hr = fmaf(u0[d], hv, hr); hz = fmaf(u0[50625+d], hv, hz); hn = fmaf(u0[101250+d], hv, hn);
      }
      ir = redkc(ir); iz = redkc(iz); inn = redkc(inn);
      hr = redkc(hr); hz = redkc(hz); hn = redkc(hn);
      if (kc == 0) {
        float r = sigf(ir + hr + a.bihSig[j]     + a.bhhSig[j]);
        float z = sigf(iz + hz + a.bihSig[225+j] + a.bhhSig[225+j]);
        float n = tanhf(inn + a.bihSig[450+j] + r*(hn + a.bhhSig[450+j]));
        float val = (1.f - z)*n + z*h[j];
        F[F_OSIG + b*225 + j] = val;
        F[F_VT   + b*452 + j] = val;
      }
    }
    gbar(ib, ep); ++ep;

    // ==== S3: out1 = relu(W1 @ osig + b1) [waves 0..224] ===================
    if (wv < 225) {
      int j = wv;
      const float* w = a.W1 + j*225;
      const float* v = F + F_OSIG + b*225;
      float acc = 0.f;
      for (int d = d0_57; d < d1_57; ++d) acc = fmaf(w[d], v[d], acc);
      acc = redkc(acc);
      if (kc == 0) F[F_OUT1 + b*225 + j] = fmaxf(acc + a.b1[j], 0.f);
    }
    gbar(ib, ep); ++ep;

    // ==== S4: hS GRU [waves 0..224], x=[out1,out7], h=hS ===================
    if (blockIdx.x < 15) {                          // out7 -> LDS
      for (int i = tid; i < 2400; i += NTH) {
        int bb = i/150, j7 = i - bb*150;
        float acc = a.b7[j7];
        const float* w  = a.W7 + j7*30;
        const float* vo = F + F_OBSD + bb*15;
        const float* vd = F + F_DY   + bb*15;
        #pragma unroll
        for (int d = 0; d < 15; ++d) acc = fmaf(w[d],    vo[d], acc);
        #pragma unroll
        for (int d = 0; d < 15; ++d) acc = fmaf(w[15+d], vd[d], acc);
        smem[i] = fmaxf(acc, 0.f);
      }
      __syncthreads();
    }
    if (wv < 225) {
      int j = wv;
      float ir=0.f, iz=0.f, inn=0.f, hr=0.f, hz=0.f, hn=0.f;
      const float* w0 = a.WihS + j*375;
      const float* x1 = F + F_OUT1 + b*225;
      for (int d = d0_57; d < d1_57; ++d) {
        float xv = x1[d];
        ir = fmaf(w0[d], xv, ir); iz = fmaf(w0[84375+d], xv, iz); inn = fmaf(w0[168750+d], xv, inn);
      }
      for (int d = d0_38; d < d1_38; ++d) {
        float xv = smem[b*150 + d];
        ir = fmaf(w0[225+d], xv, ir); iz = fmaf(w0[84600+d], xv, iz); inn = fmaf(w0[168975+d], xv, inn);
      }
      const float* u0 = a.WhhS + j*225;
      const float* h  = hSi + b*225;
      for (int d = d0_57; d < d1_57; ++d) {
        float hv = h[d];
        hr = fmaf(u0[d], hv, hr); hz = fmaf(u0[50625+d], hv, hz); hn = fmaf(u0[101250+d], hv, hn);
      }
      ir = redkc(ir); iz = redkc(iz); inn = redkc(inn);
      hr = redkc(hr); hz = redkc(hz); hn = redkc(hn);
      if (kc == 0) {
        float r = sigf(ir + hr + a.bihS[j]     + a.bhhS[j]);
        float z = sigf(iz + hz + a.bihS[225+j] + a.bhhS[225+j]);
        float n = tanhf(inn + a.bihS[450+j] + r*(hn + a.bhhS[450+j]));
        float val = (1.f - z)*n + z*h[j];
        hSo[b*225 + j]             = val;
        F[F_VT + b*452 + 225 + j]  = val;
      }
    }
    gbar(ib, ep); ++ep;

    // ==== S5: hid2 = relu(W2a @ [osig|hS] + b2a) — 4 rows/wave =============
    for (int i = tid; i < 7232; i += NTH) smem[i] = F[F_VT + i];
    __syncthreads();
    for (int g = wv; g < 4500; g += 4096) {
      const float* xr = smem + b*452;
      const float* w0 = a.W2a + (size_t)g*450;
      const int ks = kc*112;
      float a0=0.f, a1=0.f, a2=0.f, a3=0.f;
      if (!(g & 1)) {
        const float4* p0 = (const float4*)(w0 + ks);
        const float4* p1 = (const float4*)(w0 + 2025000 + ks);
        const float4* p2 = (const float4*)(w0 + 4050000 + ks);
        const float4* p3 = (const float4*)(w0 + 6075000 + ks);
        #pragma unroll 4
        for (int u = 0; u < 28; ++u) {
          float4 xa = *(const float4*)(xr + ks + 4*u);
          float4 q0 = p0[u], q1 = p1[u], q2 = p2[u], q3 = p3[u];
          a0 += q0.x*xa.x + q0.y*xa.y + q0.z*xa.z + q0.w*xa.w;
          a1 += q1.x*xa.x + q1.y*xa.y + q1.z*xa.z + q1.w*xa.w;
          a2 += q2.x*xa.x + q2.y*xa.y + q2.z*xa.z + q2.w*xa.w;
          a3 += q3.x*xa.x + q3.y*xa.y + q3.z*xa.z + q3.w*xa.w;
        }
      } else {
        const float2* p0 = (const float2*)(w0 + ks);
        const float2* p1 = (const float2*)(w0 + 2025000 + ks);
        const float2* p2 = (const float2*)(w0 + 4050000 + ks);
        const float2* p3 = (const float2*)(w0 + 6075000 + ks);
        #pragma unroll 8
        for (int u = 0; u < 56; ++u) {
          float xa = xr[ks + 2*u], xb = xr[ks + 2*u + 1];
          float2 q0 = p0[u], q1 = p1[u], q2 = p2[u], q3 = p3[u];
          a0 += q0.x*xa + q0.y*xb;  a1 += q1.x*xa + q1.y*xb;
          a2 += q2.x*xa + q2.y*xb;  a3 += q3.x*xa + q3.y*xb;
        }
      }
      if (kc == 3) {                       // k = 448, 449 tail
        float xa = xr[448], xb = xr[449];
        a0 += w0[448]*xa        + w0[449]*xb;
        a1 += w0[2025448]*xa    + w0[2025449]*xb;
        a2 += w0[4050448]*xa    + w0[4050449]*xb;
        a3 += w0[6075448]*xa    + w0[6075449]*xb;
      }
      a0 = redkc(a0); a1 = redkc(a1); a2 = redkc(a2); a3 = redkc(a3);
      if (kc == 0) {
        float* h2 = F + F_HID2 + b*18000 + g;
        h2[0]     = fmaxf(a0 + a.b2a[g],        0.f);
        h2[4500]  = fmaxf(a1 + a.b2a[g+4500],   0.f);
        h2[9000]  = fmaxf(a2 + a.b2a[g+9000],   0.f);
        h2[13500] = fmaxf(a3 + a.b2a[g+13500],  0.f);
      }
    }
    gbar(ib, ep); ++ep;

    // ==== S6: W2b partials — WG<114: (jg=WG>>1, kh=WG&1), wave i -> b=i ====
    if (blockIdx.x < 114) {
      const int kh = blockIdx.x & 1, jg = blockIdx.x >> 1;
      const int j0 = jg*4;
      const int bb = widx;
      const float4* hb = (const float4*)(F + F_HID2 + bb*18000 + kh*9000);
      const float4* w0 = (const float4*)(a.W2b + (size_t)j0*18000 + kh*9000);
      float a0=0.f, a1=0.f, a2=0.f, a3=0.f;
      if (jg < 56) {
        const float4* w1 = w0 + 4500;     // +18000 floats
        const float4* w2 = w0 + 9000;
        const float4* w3 = w0 + 13500;
        #pragma unroll 2
        for (int c = 0; c < 35; ++c) {
          int idx = c*64 + l;
          float4 h4 = hb[idx];
          float4 q0 = w0[idx], q1 = w1[idx], q2 = w2[idx], q3 = w3[idx];
          a0 += q0.x*h4.x + q0.y*h4.y + q0.z*h4.z + q0.w*h4.w;
          a1 += q1.x*h4.x + q1.y*h4.y + q1.z*h4.z + q1.w*h4.w;
          a2 += q2.x*h4.x + q2.y*h4.y + q2.z*h4.z + q2.w*h4.w;
          a3 += q3.x*h4.x + q3.y*h4.y + q3.z*h4.z + q3.w*h4.w;
        }
        if (l < 10) {
          int idx = 2240 + l;
          float4 h4 = hb[idx];
          float4 q0 = w0[idx], q1 = w1[idx], q2 = w2[idx], q3 = w3[idx];
          a0 += q0.x*h4.x + q0.y*h4.y + q0.z*h4.z + q0.w*h4.w;
          a1 += q1.x*h4.x + q1.y*h4.y + q1.z*h4.z + q1.w*h4.w;
          a2 += q2.x*h4.x + q2.y*h4.y + q2.z*h4.z + q2.w*h4.w;
          a3 += q3.x*h4.x + q3.y*h4.y + q3.z*h4.z + q3.w*h4.w;
        }
      } else {                            // jg == 56: only j = 224
        #pragma unroll 2
        for (int c = 0; c < 35; ++c) {
          int idx = c*64 + l;
          float4 h4 = hb[idx];
          float4 q0 = w0[idx];
          a0 += q0.x*h4.x + q0.y*h4.y + q0.z*h4.z + q0.w*h4.w;
        }
        if (l < 10) {
          int idx = 2240 + l;
          float4 h4 = hb[idx];
          float4 q0 = w0[idx];
          a0 += q0.x*h4.x + q0.y*h4.y + q0.z*h4.z + q0.w*h4.w;
        }
      }
      a0 = red64(a0); a1 = red64(a1); a2 = red64(a2); a3 = red64(a3);
      if (l == 0) {
        float* pp = F + F_P2 + kh*3600 + bb*225 + j0;
        pp[0] = a0;
        if (jg < 56) { pp[1] = a1; pp[2] = a2; pp[3] = a3; }
      }
    }
    gbar(ib, ep); ++ep;

    // ==== S7: out3 = relu(W3@[hS,out2]+b3+c3) ; x update [waves 0..224] ====
    if (wv < 225) {
      int j = wv;
      const float* w  = a.W3 + j*450;
      const float* v1 = hSo + b*225;
      const float* p0 = F + F_P2 + b*225;
      const float* p1 = F + F_P2 + 3600 + b*225;
      float acc = 0.f;
      for (int d = d0_57; d < d1_57; ++d) acc = fmaf(w[d], v1[d], acc);
      for (int d = d0_57; d < d1_57; ++d) acc = fmaf(w[225+d], p0[d] + p1[d], acc);
      acc = redkc(acc);
      if (kc == 0) F[F_OUT3 + b*225 + j] = fmaxf(acc + a.b3[j] + F[F_C3 + j], 0.f);
      if (j < 15 && l < 16) {
        int b2 = l, i = b2*15 + j;
        float o2   = F[F_P2 + b2*225 + j] + F[F_P2 + 3600 + b2*225 + j] + a.b2b[j];
        float xold = F[F_XP + i], dy = F[F_DY + i];
        float xnew = fmaf(o2, dy, xold);
        a.out[t*240 + i] = xnew;
        F[F_XP + i] = xnew;
        if (t + 1 < TT) {
          float o1v = a.y[(t+1)*480 + b2*30 + j];
          float o0v = a.y[t*480     + b2*30 + j];
          F[F_DY   + i] = o1v - xnew;
          F[F_OBSD + i] = o1v - o0v;
          F[F_FWD  + i] = xnew - xold;
        }
      }
    }
    gbar(ib, ep); ++ep;
  }
}

extern "C" void kernel_launch(void* const* d_in, const int* in_sizes, int n_in,
                              void* d_out, int out_size, void* d_ws, size_t ws_size,
                              hipStream_t stream) {
  (void)in_sizes; (void)n_in; (void)out_size; (void)ws_size;
  KArgs a;
  int k = 0;
  a.y      = (const float*)d_in[k++];
  a.x0     = (const float*)d_in[k++];
  a.hQ0    = (const float*)d_in[k++];
  a.hSig0  = (const float*)d_in[k++];
  a.hS0    = (const float*)d_in[k++];
  a.WihQ   = (const float*)d_in[k++];
  a.WhhQ   = (const float*)d_in[k++];
  a.bihQ   = (const float*)d_in[k++];
  a.bhhQ   = (const float*)d_in[k++];
  a.WihSig = (const float*)d_in[k++];
  a.WhhSig = (const float*)d_in[k++];
  a.bihSig = (const float*)d_in[k++];
  a.bhhSig = (const float*)d_in[k++];
  a.WihS   = (const float*)d_in[k++];
  a.WhhS   = (const float*)d_in[k++];
  a.bihS   = (const float*)d_in[k++];
  a.bhhS   = (const float*)d_in[k++];
  a.W1  = (const float*)d_in[k++];  a.b1  = (const float*)d_in[k++];
  a.W2a = (const float*)d_in[k++];  a.b2a = (const float*)d_in[k++];
  a.W2b = (const float*)d_in[k++];  a.b2b = (const float*)d_in[k++];
  a.W3  = (const float*)d_in[k++];  a.b3  = (const float*)d_in[k++];
  a.W4  = (const float*)d_in[k++];  a.b4  = (const float*)d_in[k++];
  a.W5  = (const float*)d_in[k++];  a.b5  = (const float*)d_in[k++];
  a.W6  = (const float*)d_in[k++];  a.b6  = (const float*)d_in[k++];
  a.W7  = (const float*)d_in[k++];  a.b7  = (const float*)d_in[k++];
  a.out = (float*)d_out;
  a.ib  = (int*)d_ws;
  a.fb  = (float*)((char*)d_ws + INT_TOTAL*sizeof(int));

  hipLaunchKernelGGL(knet_init, dim3(128), dim3(256), 0, stream, a);
  hipLaunchKernelGGL(knet_main, dim3(NWG), dim3(NTH), 0, stream, a);
}

// Round 3
// 68966.858 us; speedup vs baseline: 2.2674x; 1.4888x over previous
//
#include <hip/hip_runtime.h>
#include <math.h>

// ============================================================================
// KNet RNN — persistent kernel, round 3: MLP (memory-level parallelism) fix.
// 256 WGs x 1024 threads, 7 grid barriers/step.
// - __launch_bounds__(1024,4): VGPR cap 128 (was 64) -> 4x more loads in flight
// - small GEMV weights re-packed 16B-aligned in ws (strides 76/228/300/376/456)
//   with 4-aligned K-splits -> float4 loads everywhere
// - S6: 228 WGs, 4-way K-split, partials P[b][d][4] read as one float4 in S7
// - S5: batched float4 weight loads (16 in flight), x tile [b][452] in LDS
// ============================================================================

#define NWG 256
#define NTH 1024
#define WPG 16
#define TT  256
#define NEPOCH 1800
#define OFF_ATOP (NEPOCH*8)
#define OFF_GO   (NEPOCH*9)
#define INT_TOTAL 16256

// float-region offsets (all multiples of 4 -> 16B aligned)
#define F_HQ     0        // [2][16][228]
#define F_HS     7296
#define F_HSIG   14592    // [16][228]
#define F_XP     18240    // [240]
#define F_DY     18480
#define F_FWD    18720
#define F_OBSD   18960
#define F_OSIG   19200    // [16][228]
#define F_OUT1   22848    // [16][228]
#define F_OUT3   26496    // [16][228]
#define F_OUT6   30144    // [16][76]
#define F_OUT7   31360    // [16][152]
#define F_VT     33792    // [16][452]
#define F_P2     41024    // [16][228][4]
#define F_C3     55616    // [228]
#define F_HID2   55844    // [16][18000]
#define PW_IHQ   343844   // 675 x 76
#define PW_HHQ   395144   // 675 x 228
#define PW_HHSG  549044   // 675 x 228
#define PW_IHS   702944   // 675 x 376
#define PW_HHS   956744   // 675 x 228
#define PW_W1    1110644  // 225 x 228
#define PW_W3    1161944  // 225 x 456 (halves at 0 / 228)
#define PW_W4    1264544  // 225 x 456

struct KArgs {
  const float *y,*x0,*hQ0,*hSig0,*hS0;
  const float *WihQ,*WhhQ,*bihQ,*bhhQ;
  const float *WihSig,*WhhSig,*bihSig,*bhhSig;
  const float *WihS,*WhhS,*bihS,*bhhS;
  const float *W1,*b1,*W2a,*b2a,*W2b,*b2b,*W3,*b3,*W4,*b4;
  const float *W5,*b5,*W6,*b6,*W7,*b7;
  float* out;
  int*   ib;
  float* fb;
};

__device__ __forceinline__ float sigf(float x) { return 1.0f/(1.0f + __expf(-x)); }
__device__ __forceinline__ float dp4(float acc, float4 w, float4 x) {
  acc = fmaf(w.x, x.x, acc); acc = fmaf(w.y, x.y, acc);
  acc = fmaf(w.z, x.z, acc); acc = fmaf(w.w, x.w, acc);
  return acc;
}
__device__ __forceinline__ float redkc(float v) {
  v += __shfl_xor(v, 16, 64); v += __shfl_xor(v, 32, 64); return v;
}
__device__ __forceinline__ float red64(float v) {
  v += __shfl_xor(v, 1, 64);  v += __shfl_xor(v, 2, 64);
  v += __shfl_xor(v, 4, 64);  v += __shfl_xor(v, 8, 64);
  v += __shfl_xor(v, 16, 64); v += __shfl_xor(v, 32, 64);
  return v;
}

__device__ __forceinline__ void gbar(int* ib, int e) {
  __syncthreads();
  if (threadIdx.x == 0) {
    __threadfence();
    int g = (int)(blockIdx.x >> 5);
    int prev = __hip_atomic_fetch_add(ib + (e<<3) + g, 1,
                                      __ATOMIC_ACQ_REL, __HIP_MEMORY_SCOPE_AGENT);
    if (prev == 31) {
      int pt = __hip_atomic_fetch_add(ib + OFF_ATOP + e, 1,
                                      __ATOMIC_ACQ_REL, __HIP_MEMORY_SCOPE_AGENT);
      if (pt == 7)
        __hip_atomic_store(ib + OFF_GO, e, __ATOMIC_RELEASE, __HIP_MEMORY_SCOPE_AGENT);
    }
    while (__hip_atomic_load(ib + OFF_GO, __ATOMIC_RELAXED, __HIP_MEMORY_SCOPE_AGENT) < e)
      __builtin_amdgcn_s_sleep(1);
    __threadfence();
  }
  __syncthreads();
}

__global__ void knet_init(KArgs a) {
  int gt = blockIdx.x*blockDim.x + threadIdx.x;
  int nt = gridDim.x*blockDim.x;
  float* F = a.fb;
  for (int i = gt; i < INT_TOTAL; i += nt) a.ib[i] = (i == OFF_GO) ? -1 : 0;
  for (int i = gt; i < 3600; i += nt) {
    int b = i/225, j = i - b*225;
    F[F_HQ   + b*228 + j] = a.hQ0[i];
    F[F_HS   + b*228 + j] = a.hS0[i];
    F[F_HSIG + b*228 + j] = a.hSig0[i];
  }
  for (int i = gt; i < 240; i += nt) {
    int b = i/15, j = i - b*15;
    float xv = a.x0[i];
    float ob = a.y[b*30 + j];
    F[F_XP+i]=xv; F[F_DY+i]=ob-xv; F[F_OBSD+i]=ob-xv; F[F_FWD+i]=0.f;
  }
  for (int j = gt; j < 225; j += nt) {
    float acc = 0.f;
    const float* w = a.W3 + j*450 + 225;
    for (int d = 0; d < 225; ++d) acc += w[d]*a.b2b[d];
    F[F_C3+j] = acc;
  }
  for (int i = gt; i < 675*75;  i += nt){ int r=i/75,  d=i-r*75;  F[PW_IHQ  + r*76  + d] = a.WihQ[i]; }
  for (int i = gt; i < 675*225; i += nt){ int r=i/225, d=i-r*225; F[PW_HHQ  + r*228 + d] = a.WhhQ[i]; }
  for (int i = gt; i < 675*225; i += nt){ int r=i/225, d=i-r*225; F[PW_HHSG + r*228 + d] = a.WhhSig[i]; }
  for (int i = gt; i < 675*375; i += nt){ int r=i/375, d=i-r*375; F[PW_IHS  + r*376 + d] = a.WihS[i]; }
  for (int i = gt; i < 675*225; i += nt){ int r=i/225, d=i-r*225; F[PW_HHS  + r*228 + d] = a.WhhS[i]; }
  for (int i = gt; i < 225*225; i += nt){ int r=i/225, d=i-r*225; F[PW_W1   + r*228 + d] = a.W1[i]; }
  for (int i = gt; i < 225*450; i += nt){ int r=i/450, d=i-r*450; F[PW_W3 + r*456 + (d<225?d:d+3)] = a.W3[i]; }
  for (int i = gt; i < 225*450; i += nt){ int r=i/450, d=i-r*450; F[PW_W4 + r*456 + (d<225?d:d+3)] = a.W4[i]; }
}

__global__ __launch_bounds__(NTH, 4) void knet_main(KArgs a) {
  __shared__ float smem[7232];
  const int tid  = threadIdx.x;
  const int widx = tid >> 6;
  const int l    = tid & 63;
  const int b    = l & 15;
  const int kc   = l >> 4;
  const int bx   = (int)blockIdx.x;
  const int wv   = bx * WPG + widx;
  float* F  = a.fb;
  int*   ib = a.ib;
  int ep = 0;

  // 4-aligned K-split slices
  const int o225 = kc*60,  n225 = (kc<3)?15:11;   // + scalar tail d=224 (kc==3)
  const int o75  = kc*20,  n75  = (kc<3)?5:3;     // + scalar tail d=72..74
  const int o300 = kc*76,  n300 = (kc<3)?19:18;
  const int o375 = kc*96,  n375 = (kc<3)?24:21;   // + scalar tail d=372..374

  for (int t = 0; t < TT; ++t) {
    const int p = t & 1, q = p ^ 1;
    float* hQi = F + F_HQ + p*3648;  float* hQo = F + F_HQ + q*3648;
    float* hSi = F + F_HS + p*3648;  float* hSo = F + F_HS + q*3648;

    // ==== S01: hSig (out4) [wv<225] + hQ GRU [225<=wv<450] + out6/out7 =====
    if (bx >= 14 && bx < 29) {          // stage out5 [b][76] into LDS
      for (int i = tid; i < 1216; i += NTH) {
        int bb = i/76, j5 = i - bb*76;
        if (j5 < 75) {
          float acc = a.b5[j5];
          const float* w = a.W5 + j5*15;
          const float* v = F + F_FWD + bb*15;
          #pragma unroll
          for (int d = 0; d < 15; ++d) acc = fmaf(w[d], v[d], acc);
          smem[i] = fmaxf(acc, 0.f);
        }
      }
      __syncthreads();
    }
    if (wv < 225) {                     // hSig = relu(W4 @ [osig,out3] + b4)
      if (t > 0) {
        int j = wv;
        const float* wA = F + PW_W4 + (size_t)j*456;
        const float* wB = wA + 228;
        const float* x1 = F + F_OSIG + b*228;
        const float* x2 = F + F_OUT3 + b*228;
        const float4* wA4 = (const float4*)(wA + o225);
        const float4* wB4 = (const float4*)(wB + o225);
        const float4* x14 = (const float4*)(x1 + o225);
        const float4* x24 = (const float4*)(x2 + o225);
        float acc = 0.f;
        #pragma unroll 4
        for (int u = 0; u < n225; ++u) acc = dp4(acc, wA4[u], x14[u]);
        #pragma unroll 4
        for (int u = 0; u < n225; ++u) acc = dp4(acc, wB4[u], x24[u]);
        if (kc == 3) { acc = fmaf(wA[224], x1[224], acc); acc = fmaf(wB[224], x2[224], acc); }
        acc = redkc(acc);
        if (kc == 0) F[F_HSIG + b*228 + wv] = fmaxf(acc + a.b4[wv], 0.f);
      }
    } else if (wv < 450) {              // hQ GRU, x = out5 (LDS)
      int j = wv - 225;
      float ir=0,iz=0,inn=0,hr=0,hz=0,hn=0;
      {
        const float* w0s = F + PW_IHQ + (size_t)j*76;
        const float* w1s = F + PW_IHQ + (size_t)(225+j)*76;
        const float* w2s = F + PW_IHQ + (size_t)(450+j)*76;
        const float* xs  = smem + b*76;
        const float4* w04=(const float4*)(w0s+o75), *w14=(const float4*)(w1s+o75),
                    *w24=(const float4*)(w2s+o75), *x4=(const float4*)(xs+o75);
        #pragma unroll
        for (int u = 0; u < n75; ++u) { float4 xv=x4[u];
          ir=dp4(ir,w04[u],xv); iz=dp4(iz,w14[u],xv); inn=dp4(inn,w24[u],xv); }
        if (kc == 3) {
          #pragma unroll
          for (int d = 72; d < 75; ++d) { float xv=xs[d];
            ir=fmaf(w0s[d],xv,ir); iz=fmaf(w1s[d],xv,iz); inn=fmaf(w2s[d],xv,inn); }
        }
      }
      {
        const float* u0s = F + PW_HHQ + (size_t)j*228;
        const float* u1s = F + PW_HHQ + (size_t)(225+j)*228;
        const float* u2s = F + PW_HHQ + (size_t)(450+j)*228;
        const float* hs  = hQi + b*228;
        const float4* u04=(const float4*)(u0s+o225), *u14=(const float4*)(u1s+o225),
                    *u24=(const float4*)(u2s+o225), *h4=(const float4*)(hs+o225);
        #pragma unroll 4
        for (int u = 0; u < n225; ++u) { float4 hv=h4[u];
          hr=dp4(hr,u04[u],hv); hz=dp4(hz,u14[u],hv); hn=dp4(hn,u24[u],hv); }
        if (kc == 3) { float hv=hs[224];
          hr=fmaf(u0s[224],hv,hr); hz=fmaf(u1s[224],hv,hz); hn=fmaf(u2s[224],hv,hn); }
      }
      ir=redkc(ir); iz=redkc(iz); inn=redkc(inn);
      hr=redkc(hr); hz=redkc(hz); hn=redkc(hn);
      if (kc == 0) {
        float r = sigf(ir + hr + a.bihQ[j]     + a.bhhQ[j]);
        float z = sigf(iz + hz + a.bihQ[225+j] + a.bhhQ[225+j]);
        float n = tanhf(inn + a.bihQ[450+j] + r*(hn + a.bhhQ[450+j]));
        hQo[b*228 + j] = (1.f - z)*n + z*hQi[b*228 + j];
      }
    }
    if (bx == 30) {                     // out6 -> global [b][76]
      for (int i = tid; i < 1200; i += NTH) {
        int bb = i/75, j6 = i - bb*75;
        float acc = a.b6[j6];
        const float* w = a.W6 + j6*15;
        const float* v = F + F_FWD + bb*15;
        #pragma unroll
        for (int d = 0; d < 15; ++d) acc = fmaf(w[d], v[d], acc);
        F[F_OUT6 + bb*76 + j6] = fmaxf(acc, 0.f);
      }
    } else if (bx == 31) {              // out7 -> global [b][152]
      for (int i = tid; i < 2400; i += NTH) {
        int bb = i/150, j7 = i - bb*150;
        float acc = a.b7[j7];
        const float* w  = a.W7 + j7*30;
        const float* vo = F + F_OBSD + bb*15;
        const float* vd = F + F_DY   + bb*15;
        #pragma unroll
        for (int d = 0; d < 15; ++d) acc = fmaf(w[d],    vo[d], acc);
        #pragma unroll
        for (int d = 0; d < 15; ++d) acc = fmaf(w[15+d], vd[d], acc);
        F[F_OUT7 + bb*152 + j7] = fmaxf(acc, 0.f);
      }
    }
    gbar(ib, ep); ++ep;

    // ==== S2: osig GRU [wv<225], x = [hQ|out6] staged in LDS ===============
    if (bx < 15) {
      for (int i = tid; i < 4800; i += NTH) {
        int bb = i/300, d = i - bb*300;
        smem[i] = (d < 225) ? hQo[bb*228 + d] : F[F_OUT6 + bb*76 + (d-225)];
      }
      __syncthreads();
    }
    if (wv < 225) {
      int j = wv;
      float ir=0,iz=0,inn=0,hr=0,hz=0,hn=0;
      {
        const float* w0s = a.WihSig + (size_t)j*300;
        const float* w1s = a.WihSig + (size_t)(225+j)*300;
        const float* w2s = a.WihSig + (size_t)(450+j)*300;
        const float* xs  = smem + b*300;
        const float4* w04=(const float4*)(w0s+o300), *w14=(const float4*)(w1s+o300),
                    *w24=(const float4*)(w2s+o300), *x4=(const float4*)(xs+o300);
        #pragma unroll 4
        for (int u = 0; u < n300; ++u) { float4 xv=x4[u];
          ir=dp4(ir,w04[u],xv); iz=dp4(iz,w14[u],xv); inn=dp4(inn,w24[u],xv); }
      }
      {
        const float* u0s = F + PW_HHSG + (size_t)j*228;
        const float* u1s = F + PW_HHSG + (size_t)(225+j)*228;
        const float* u2s = F + PW_HHSG + (size_t)(450+j)*228;
        const float* hs  = F + F_HSIG + b*228;
        const float4* u04=(const float4*)(u0s+o225), *u14=(const float4*)(u1s+o225),
                    *u24=(const float4*)(u2s+o225), *h4=(const float4*)(hs+o225);
        #pragma unroll 4
        for (int u = 0; u < n225; ++u) { float4 hv=h4[u];
          hr=dp4(hr,u04[u],hv); hz=dp4(hz,u14[u],hv); hn=dp4(hn,u24[u],hv); }
        if (kc == 3) { float hv=hs[224];
          hr=fmaf(u0s[224],hv,hr); hz=fmaf(u1s[224],hv,hz); hn=fmaf(u2s[224],hv,hn); }
      }
      ir=redkc(ir); iz=redkc(iz); inn=redkc(inn);
      hr=redkc(hr); hz=redkc(hz); hn=redkc(hn);
      if (kc == 0) {
        float r = sigf(ir + hr + a.bihSig[j]     + a.bhhSig[j]);
        float z = sigf(iz + hz + a.bihSig[225+j] + a.bhhSig[225+j]);
        float n = tanhf(inn + a.bihSig[450+j] + r*(hn + a.bhhSig[450+j]));
        float val = (1.f - z)*n + z*F[F_HSIG + b*228 + j];
        F[F_OSIG + b*228 + j] = val;
        F[F_VT   + b*452 + j] = val;
      }
    }
    gbar(ib, ep); ++ep;

    // ==== S3: out1 = relu(W1 @ osig + b1) [wv<225] =========================
    if (wv < 225) {
      int j = wv;
      const float* ws = F + PW_W1 + (size_t)j*228;
      const float* xs = F + F_OSIG + b*228;
      const float4* w4=(const float4*)(ws+o225), *x4=(const float4*)(xs+o225);
      float acc = 0.f;
      #pragma unroll 4
      for (int u = 0; u < n225; ++u) acc = dp4(acc, w4[u], x4[u]);
      if (kc == 3) acc = fmaf(ws[224], xs[224], acc);
      acc = redkc(acc);
      if (kc == 0) F[F_OUT1 + b*228 + j] = fmaxf(acc + a.b1[j], 0.f);
    }
    gbar(ib, ep); ++ep;

    // ==== S4: hS GRU [wv<225], x = [out1|out7] staged in LDS ===============
    if (bx < 15) {
      for (int i = tid; i < 6016; i += NTH) {
        int bb = i/376, d = i - bb*376;
        float v = 0.f;
        if (d < 225) v = F[F_OUT1 + bb*228 + d];
        else if (d < 375) v = F[F_OUT7 + bb*152 + (d-225)];
        smem[i] = v;
      }
      __syncthreads();
    }
    if (wv < 225) {
      int j = wv;
      float ir=0,iz=0,inn=0,hr=0,hz=0,hn=0;
      {
        const float* w0s = F + PW_IHS + (size_t)j*376;
        const float* w1s = F + PW_IHS + (size_t)(225+j)*376;
        const float* w2s = F + PW_IHS + (size_t)(450+j)*376;
        const float* xs  = smem + b*376;
        const float4* w04=(const float4*)(w0s+o375), *w14=(const float4*)(w1s+o375),
                    *w24=(const float4*)(w2s+o375), *x4=(const float4*)(xs+o375);
        #pragma unroll 4
        for (int u = 0; u < n375; ++u) { float4 xv=x4[u];
          ir=dp4(ir,w04[u],xv); iz=dp4(iz,w14[u],xv); inn=dp4(inn,w24[u],xv); }
        if (kc == 3) {
          #pragma unroll
          for (int d = 372; d < 375; ++d) { float xv=xs[d];
            ir=fmaf(w0s[d],xv,ir); iz=fmaf(w1s[d],xv,iz); inn=fmaf(w2s[d],xv,inn); }
        }
      }
      {
        const float* u0s = F + PW_HHS + (size_t)j*228;
        const float* u1s = F + PW_HHS + (size_t)(225+j)*228;
        const float* u2s = F + PW_HHS + (size_t)(450+j)*228;
        const float* hs  = hSi + b*228;
        const float4* u04=(const float4*)(u0s+o225), *u14=(const float4*)(u1s+o225),
                    *u24=(const float4*)(u2s+o225), *h4=(const float4*)(hs+o225);
        #pragma unroll 4
        for (int u = 0; u < n225; ++u) { float4 hv=h4[u];
          hr=dp4(hr,u04[u],hv); hz=dp4(hz,u14[u],hv); hn=dp4(hn,u24[u],hv); }
        if (kc == 3) { float hv=hs[224];
          hr=fmaf(u0s[224],hv,hr); hz=fmaf(u1s[224],hv,hz); hn=fmaf(u2s[224],hv,hn); }
      }
      ir=redkc(ir); iz=redkc(iz); inn=redkc(inn);
      hr=redkc(hr); hz=redkc(hz); hn=redkc(hn);
      if (kc == 0) {
        float r = sigf(ir + hr + a.bihS[j]     + a.bhhS[j]);
        float z = sigf(iz + hz + a.bihS[225+j] + a.bhhS[225+j]);
        float n = tanhf(inn + a.bihS[450+j] + r*(hn + a.bhhS[450+j]));
        float val = (1.f - z)*n + z*hSi[b*228 + j];
        hSo[b*228 + j]            = val;
        F[F_VT + b*452 + 225 + j] = val;
      }
    }
    gbar(ib, ep); ++ep;

    // ==== S5: hid2 = relu(W2a @ [osig|hS] + b2a) — batched float4 loads ====
    {
      const float4* src = (const float4*)(F + F_VT);
      for (int i = tid; i < 1808; i += NTH) ((float4*)smem)[i] = src[i];
    }
    __syncthreads();
    for (int g = wv; g < 4500; g += 4096) {
      const float* xr = smem + b*452 + kc*112;
      const float4* xr4 = (const float4*)xr;
      float a0=0.f, a1=0.f, a2=0.f, a3=0.f;
      const size_t base = (size_t)g*450 + kc*112;
      if (!(g & 1)) {
        const float4* p0 = (const float4*)(a.W2a + base);
        const float4* p1 = (const float4*)(a.W2a + base + 2025000);
        const float4* p2 = (const float4*)(a.W2a + base + 4050000);
        const float4* p3 = (const float4*)(a.W2a + base + 6075000);
        for (int c = 0; c < 7; ++c) {
          float4 xa=xr4[4*c], xb=xr4[4*c+1], xc=xr4[4*c+2], xd=xr4[4*c+3];
          float4 w00=p0[4*c],w01=p0[4*c+1],w02=p0[4*c+2],w03=p0[4*c+3];
          float4 w10=p1[4*c],w11=p1[4*c+1],w12=p1[4*c+2],w13=p1[4*c+3];
          float4 w20=p2[4*c],w21=p2[4*c+1],w22=p2[4*c+2],w23=p2[4*c+3];
          float4 w30=p3[4*c],w31=p3[4*c+1],w32=p3[4*c+2],w33=p3[4*c+3];
          a0 = dp4(dp4(dp4(dp4(a0,w00,xa),w01,xb),w02,xc),w03,xd);
          a1 = dp4(dp4(dp4(dp4(a1,w10,xa),w11,xb),w12,xc),w13,xd);
          a2 = dp4(dp4(dp4(dp4(a2,w20,xa),w21,xb),w22,xc),w23,xd);
          a3 = dp4(dp4(dp4(dp4(a3,w30,xa),w31,xb),w32,xc),w33,xd);
        }
      } else {
        const float2* p0 = (const float2*)(a.W2a + base);
        const float2* p1 = (const float2*)(a.W2a + base + 2025000);
        const float2* p2 = (const float2*)(a.W2a + base + 4050000);
        const float2* p3 = (const float2*)(a.W2a + base + 6075000);
        #pragma unroll 8
        for (int u = 0; u < 56; ++u) {
          float xa = xr[2*u], xb = xr[2*u+1];
          float2 q0=p0[u], q1=p1[u], q2=p2[u], q3=p3[u];
          a0 = fmaf(q0.y, xb, fmaf(q0.x, xa, a0));
          a1 = fmaf(q1.y, xb, fmaf(q1.x, xa, a1));
          a2 = fmaf(q2.y, xb, fmaf(q2.x, xa, a2));
          a3 = fmaf(q3.y, xb, fmaf(q3.x, xa, a3));
        }
      }
      if (kc == 3) {                    // d = 448,449 tail
        float xa = xr[112], xb = xr[113];
        const float* w = a.W2a + base + 112;
        a0 = fmaf(w[1], xb, fmaf(w[0], xa, a0));
        a1 = fmaf(w[2025001], xb, fmaf(w[2025000], xa, a1));
        a2 = fmaf(w[4050001], xb, fmaf(w[4050000], xa, a2));
        a3 = fmaf(w[6075001], xb, fmaf(w[6075000], xa, a3));
      }
      a0=redkc(a0); a1=redkc(a1); a2=redkc(a2); a3=redkc(a3);
      if (kc == 0) {
        float* h2 = F + F_HID2 + b*18000 + g;
        h2[0]     = fmaxf(a0 + a.b2a[g],       0.f);
        h2[4500]  = fmaxf(a1 + a.b2a[g+4500],  0.f);
        h2[9000]  = fmaxf(a2 + a.b2a[g+9000],  0.f);
        h2[13500] = fmaxf(a3 + a.b2a[g+13500], 0.f);
      }
    }
    gbar(ib, ep); ++ep;

    // ==== S6: W2b partials — 228 WGs: (jg=bx>>2, kq=bx&3), wave = b ========
    if (bx < 228) {
      const int jg = bx >> 2, kq = bx & 3, j0 = jg*4;
      const int nr = (jg == 56) ? 1 : 4;
      const float4* hb = (const float4*)(F + F_HID2 + (size_t)widx*18000) + kq*1125;
      const float4* w0 = (const float4*)a.W2b + (size_t)j0*4500 + kq*1125;
      const float4* w1 = (nr>1) ? ((const float4*)a.W2b + (size_t)(j0+1)*4500 + kq*1125) : w0;
      const float4* w2 = (nr>1) ? ((const float4*)a.W2b + (size_t)(j0+2)*4500 + kq*1125) : w0;
      const float4* w3 = (nr>1) ? ((const float4*)a.W2b + (size_t)(j0+3)*4500 + kq*1125) : w0;
      float a0=0.f, a1=0.f, a2=0.f, a3=0.f;
      #pragma unroll 2
      for (int c = 0; c < 17; ++c) {
        int idx = c*64 + l;
        float4 h4 = hb[idx];
        float4 q0=w0[idx], q1=w1[idx], q2=w2[idx], q3=w3[idx];
        a0 = dp4(a0,q0,h4); a1 = dp4(a1,q1,h4); a2 = dp4(a2,q2,h4); a3 = dp4(a3,q3,h4);
      }
      if (l < 37) {
        int idx = 1088 + l;
        float4 h4 = hb[idx];
        float4 q0=w0[idx], q1=w1[idx], q2=w2[idx], q3=w3[idx];
        a0 = dp4(a0,q0,h4); a1 = dp4(a1,q1,h4); a2 = dp4(a2,q2,h4); a3 = dp4(a3,q3,h4);
      }
      a0=red64(a0); a1=red64(a1); a2=red64(a2); a3=red64(a3);
      if (l == 0) {
        float* pp = F + F_P2 + ((widx*228 + j0) << 2) + kq;
        pp[0] = a0;
        if (nr > 1) { pp[4] = a1; pp[8] = a2; pp[12] = a3; }
      }
    }
    gbar(ib, ep); ++ep;

    // ==== S7: out3 = relu(W3@[hS|out2]+b3+c3) ; x update [wv<225] ==========
    if (wv < 225) {
      int j = wv;
      const float* wA = F + PW_W3 + (size_t)j*456;
      const float* wB = wA + 228;
      const float* x1 = hSo + b*228;
      const float* Pb = F + F_P2 + ((b*228) << 2);
      const float4* wA4=(const float4*)(wA+o225), *x14=(const float4*)(x1+o225);
      const float4* wB4=(const float4*)(wB+o225);
      float acc = 0.f;
      #pragma unroll 4
      for (int u = 0; u < n225; ++u) acc = dp4(acc, wA4[u], x14[u]);
      if (kc == 3) acc = fmaf(wA[224], x1[224], acc);
      #pragma unroll 2
      for (int u = 0; u < n225; ++u) {
        int d = o225 + 4*u;
        float4 wq = wB4[u];
        float4 pa = *(const float4*)(Pb + ((d+0)<<2));
        float4 pb = *(const float4*)(Pb + ((d+1)<<2));
        float4 pc = *(const float4*)(Pb + ((d+2)<<2));
        float4 pd = *(const float4*)(Pb + ((d+3)<<2));
        acc = fmaf(wq.x, pa.x+pa.y+pa.z+pa.w, acc);
        acc = fmaf(wq.y, pb.x+pb.y+pb.z+pb.w, acc);
        acc = fmaf(wq.z, pc.x+pc.y+pc.z+pc.w, acc);
        acc = fmaf(wq.w, pd.x+pd.y+pd.z+pd.w, acc);
      }
      if (kc == 3) {
        float4 pt = *(const float4*)(Pb + (224<<2));
        acc = fmaf(wB[224], pt.x+pt.y+pt.z+pt.w, acc);
      }
      acc = redkc(acc);
      if (kc == 0) F[F_OUT3 + b*228 + j] = fmaxf(acc + a.b3[j] + F[F_C3 + j], 0.f);
      if (j < 15 && l < 16) {
        int b2 = l, i = b2*15 + j;
        float4 pq = *(const float4*)(F + F_P2 + ((b2*228 + j) << 2));
        float o2 = pq.x + pq.y + pq.z + pq.w + a.b2b[j];
        float xold = F[F_XP + i], dy = F[F_DY + i];
        float xnew = fmaf(o2, dy, xold);
        a.out[t*240 + i] = xnew;
        F[F_XP + i] = xnew;
        if (t + 1 < TT) {
          float o1v = a.y[(t+1)*480 + b2*30 + j];
          float o0v = a.y[t*480     + b2*30 + j];
          F[F_DY   + i] = o1v - xnew;
          F[F_OBSD + i] = o1v - o0v;
          F[F_FWD  + i] = xnew - xold;
        }
      }
    }
    gbar(ib, ep); ++ep;
  }
}

extern "C" void kernel_launch(void* const* d_in, const int* in_sizes, int n_in,
                              void* d_out, int out_size, void* d_ws, size_t ws_size,
                              hipStream_t stream) {
  (void)in_sizes; (void)n_in; (void)out_size; (void)ws_size;
  KArgs a;
  int k = 0;
  a.y      = (const float*)d_in[k++];
  a.x0     = (const float*)d_in[k++];
  a.hQ0    = (const float*)d_in[k++];
  a.hSig0  = (const float*)d_in[k++];
  a.hS0    = (const float*)d_in[k++];
  a.WihQ   = (const float*)d_in[k++];
  a.WhhQ   = (const float*)d_in[k++];
  a.bihQ   = (const float*)d_in[k++];
  a.bhhQ   = (const float*)d_in[k++];
  a.WihSig = (const float*)d_in[k++];
  a.WhhSig = (const float*)d_in[k++];
  a.bihSig = (const float*)d_in[k++];
  a.bhhSig = (const float*)d_in[k++];
  a.WihS   = (const float*)d_in[k++];
  a.WhhS   = (const float*)d_in[k++];
  a.bihS   = (const float*)d_in[k++];
  a.bhhS   = (const float*)d_in[k++];
  a.W1  = (const float*)d_in[k++];  a.b1  = (const float*)d_in[k++];
  a.W2a = (const float*)d_in[k++];  a.b2a = (const float*)d_in[k++];
  a.W2b = (const float*)d_in[k++];  a.b2b = (const float*)d_in[k++];
  a.W3  = (const float*)d_in[k++];  a.b3  = (const float*)d_in[k++];
  a.W4  = (const float*)d_in[k++];  a.b4  = (const float*)d_in[k++];
  a.W5  = (const float*)d_in[k++];  a.b5  = (const float*)d_in[k++];
  a.W6  = (const float*)d_in[k++];  a.b6  = (const float*)d_in[k++];
  a.W7  = (const float*)d_in[k++];  a.b7  = (const float*)d_in[k++];
  a.out = (float*)d_out;
  a.ib  = (int*)d_ws;
  a.fb  = (float*)((char*)d_ws + INT_TOTAL*sizeof(int));

  hipLaunchKernelGGL(knet_init, dim3(256), dim3(256), 0, stream, a);
  hipLaunchKernelGGL(knet_main, dim3(NWG), dim3(NTH), 0, stream, a);
}

// Round 4
// 50615.109 us; speedup vs baseline: 3.0895x; 1.3626x over previous
//
#include <hip/hip_runtime.h>
#include <math.h>

// ============================================================================
// KNet RNN — persistent kernel, round 4: distinct-coalesced loads everywhere.
// WG j owns row j of every small GEMV (225 WGs), wave = batch b, 64-way
// K-split per wave (red64). Weights repacked [Wih|Whh] padded rows.
// S5: W2aP[18000][452], wave = 2 rows x 16 b, lanes span K (coalesced),
// x from LDS [16][452] (conflict-free float4). 7 grid barriers/step.
// ============================================================================

#define NWG 256
#define NTH 1024
#define TT  256
#define NEPOCH 1800
#define OFF_ATOP (NEPOCH*8)
#define OFF_GO   (NEPOCH*9)
#define INT_TOTAL 16256

// float-region offsets
#define F_HQ    0         // [2][16][228]
#define F_HS    7296      // [2][16][228]
#define F_HSIG  14592     // [16][228]
#define F_XP    18240     // [240]
#define F_DY    18480     // [16][16]
#define F_FWD   18736     // [16][16]
#define F_OBSD  18992     // [16][16]
#define F_OSIG  19248     // [16][228]
#define F_OUT1  22896     // [16][228]
#define F_OUT3  26544     // [16][228]
#define F_XV    30192     // [16][452]  x for W2a: [b][osig|hS]
#define F_P2    37424     // [16][228][4]
#define F_HID2  52016     // [16][18000]
#define PQ      340016    // 675 x 304  [Wih 75 pad 76 | Whh 225 pad 228]
#define PSIG    545216    // 675 x 544  [225 pad 228 | 75 pad 76 | 225 pad 228 | pad 544]
#define PS      912416    // 675 x 608  [225 pad 228 | 150 pad 152 | 225 pad 228]
#define PW1     1322816   // 225 x 228
#define PW3     1374116   // 225 x 456  [225 pad 228 | 225 pad 228]
#define PW4     1476716   // 225 x 456
#define PW5     1579316   // 75 x 16
#define PW6     1580516   // 75 x 16
#define PW7     1581716   // 150 x 32   [15 pad 16 | 15 pad 16]
#define W2AP    1586516   // 18000 x 452

// LDS layout (floats) — unioned by stage lifetime
#define L_OUT5 0      // [16][76]   stage A
#define L_OUT6 1216   // [16][76]   stage B
#define L_OUT7 2432   // [16][152]  stage D
#define L_OUT2 4864   // [16][228]  stage G
#define L_XV   0      // [16][452]  stage E
#define L_TOTAL 8512

struct KArgs {
  const float *y,*x0,*hQ0,*hSig0,*hS0;
  const float *WihQ,*WhhQ,*bihQ,*bhhQ;
  const float *WihSig,*WhhSig,*bihSig,*bhhSig;
  const float *WihS,*WhhS,*bihS,*bhhS;
  const float *W1,*b1,*W2a,*b2a,*W2b,*b2b,*W3,*b3,*W4,*b4;
  const float *W5,*b5,*W6,*b6,*W7,*b7;
  float* out;
  int*   ib;
  float* fb;
};

__device__ __forceinline__ float sigf(float x) { return 1.0f/(1.0f + __expf(-x)); }
__device__ __forceinline__ float dp4(float acc, float4 w, float4 x) {
  acc = fmaf(w.x, x.x, acc); acc = fmaf(w.y, x.y, acc);
  acc = fmaf(w.z, x.z, acc); acc = fmaf(w.w, x.w, acc);
  return acc;
}
__device__ __forceinline__ float4 ldg4(const float* p){ return *(const float4*)p; }
__device__ __forceinline__ float red64(float v) {
  v += __shfl_xor(v, 1, 64);  v += __shfl_xor(v, 2, 64);
  v += __shfl_xor(v, 4, 64);  v += __shfl_xor(v, 8, 64);
  v += __shfl_xor(v, 16, 64); v += __shfl_xor(v, 32, 64);
  return v;
}

__device__ __forceinline__ void gbar(int* ib, int e) {
  __syncthreads();
  if (threadIdx.x == 0) {
    __threadfence();
    int g = (int)(blockIdx.x >> 5);
    int prev = __hip_atomic_fetch_add(ib + (e<<3) + g, 1,
                                      __ATOMIC_ACQ_REL, __HIP_MEMORY_SCOPE_AGENT);
    if (prev == 31) {
      int pt = __hip_atomic_fetch_add(ib + OFF_ATOP + e, 1,
                                      __ATOMIC_ACQ_REL, __HIP_MEMORY_SCOPE_AGENT);
      if (pt == 7)
        __hip_atomic_store(ib + OFF_GO, e, __ATOMIC_RELEASE, __HIP_MEMORY_SCOPE_AGENT);
    }
    while (__hip_atomic_load(ib + OFF_GO, __ATOMIC_RELAXED, __HIP_MEMORY_SCOPE_AGENT) < e)
      __builtin_amdgcn_s_sleep(1);
    __threadfence();
  }
  __syncthreads();
}

__global__ void knet_init(KArgs a) {
  int gt = blockIdx.x*blockDim.x + threadIdx.x;
  int nt = gridDim.x*blockDim.x;
  float* F = a.fb;
  for (int i = gt; i < INT_TOTAL; i += nt) a.ib[i] = (i == OFF_GO) ? -1 : 0;
  for (int i = gt; i < 3648; i += nt) {
    int b = i/228, j = i - b*228;
    float hq=0.f, hs=0.f, hg=0.f;
    if (j < 225) { hq = a.hQ0[b*225+j]; hs = a.hS0[b*225+j]; hg = a.hSig0[b*225+j]; }
    F[F_HQ + i] = hq; F[F_HS + i] = hs; F[F_HSIG + i] = hg;
  }
  for (int i = gt; i < 240; i += nt) F[F_XP + i] = a.x0[i];
  for (int i = gt; i < 256; i += nt) {
    int b = i >> 4, j = i & 15;
    float dy=0.f, od=0.f;
    if (j < 15) {
      float ob = a.y[b*30 + j], xv = a.x0[b*15 + j];
      dy = ob - xv; od = ob - xv;
    }
    F[F_DY + i] = dy; F[F_OBSD + i] = od; F[F_FWD + i] = 0.f;
  }
  // packed weights (pads written as explicit zeros; single pass, no races)
  for (int i = gt; i < 675*304; i += nt) {
    int r = i/304, d = i - r*304; float v = 0.f;
    if (d < 75) v = a.WihQ[r*75 + d];
    else if (d >= 76 && d < 301) v = a.WhhQ[r*225 + d - 76];
    F[PQ + i] = v;
  }
  for (int i = gt; i < 675*544; i += nt) {
    int r = i/544, d = i - r*544; float v = 0.f;
    if (d < 225) v = a.WihSig[r*300 + d];
    else if (d >= 228 && d < 303) v = a.WihSig[r*300 + 225 + d - 228];
    else if (d >= 304 && d < 529) v = a.WhhSig[r*225 + d - 304];
    F[PSIG + i] = v;
  }
  for (int i = gt; i < 675*608; i += nt) {
    int r = i/608, d = i - r*608; float v = 0.f;
    if (d < 225) v = a.WihS[r*375 + d];
    else if (d >= 228 && d < 378) v = a.WihS[r*375 + 225 + d - 228];
    else if (d >= 380 && d < 605) v = a.WhhS[r*225 + d - 380];
    F[PS + i] = v;
  }
  for (int i = gt; i < 225*228; i += nt) {
    int r = i/228, d = i - r*228;
    F[PW1 + i] = (d < 225) ? a.W1[r*225 + d] : 0.f;
  }
  for (int i = gt; i < 225*456; i += nt) {
    int r = i/456, d = i - r*456; float v3 = 0.f, v4 = 0.f;
    if (d < 225)               { v3 = a.W3[r*450 + d];           v4 = a.W4[r*450 + d]; }
    else if (d >= 228 && d < 453) { v3 = a.W3[r*450 + 225 + d - 228]; v4 = a.W4[r*450 + 225 + d - 228]; }
    F[PW3 + i] = v3; F[PW4 + i] = v4;
  }
  for (int i = gt; i < 75*16; i += nt) {
    int r = i >> 4, d = i & 15;
    F[PW5 + i] = (d < 15) ? a.W5[r*15 + d] : 0.f;
    F[PW6 + i] = (d < 15) ? a.W6[r*15 + d] : 0.f;
  }
  for (int i = gt; i < 150*32; i += nt) {
    int r = i >> 5, d = i & 31; float v = 0.f;
    if (d < 15) v = a.W7[r*30 + d];
    else if (d >= 16 && d < 31) v = a.W7[r*30 + 15 + d - 16];
    F[PW7 + i] = v;
  }
  for (long long i = gt; i < 18000LL*452; i += nt) {
    long long r = i/452; int d = (int)(i - r*452);
    F[W2AP + i] = (d < 450) ? a.W2a[r*450 + d] : 0.f;
  }
}

__global__ __launch_bounds__(NTH, 4) void knet_main(KArgs a) {
  __shared__ float smem[L_TOTAL];
  const int tid  = threadIdx.x;
  const int widx = tid >> 6;        // wave index == batch b in small stages
  const int l    = tid & 63;
  const int bx   = (int)blockIdx.x;
  const int k0   = l*4;
  float* F  = a.fb;
  int*   ib = a.ib;
  int ep = 0;

  for (int t = 0; t < TT; ++t) {
    const int p = t & 1, q = p ^ 1;
    float* hQi = F + F_HQ + p*3648;  float* hQo = F + F_HQ + q*3648;
    float* hSi = F + F_HS + p*3648;  float* hSo = F + F_HS + q*3648;

    // ==== A: out5(LDS) ; hQ GRU ; hSig = out4(prev osig,out3) ==============
    if (bx < 225) {
      for (int i = tid; i < 1200; i += NTH) {
        int bb = i/75, j5 = i - bb*75;
        const float4* w  = (const float4*)(F + PW5 + j5*16);
        const float4* xv = (const float4*)(F + F_FWD + bb*16);
        float acc = a.b5[j5];
        acc = dp4(acc, w[0], xv[0]); acc = dp4(acc, w[1], xv[1]);
        acc = dp4(acc, w[2], xv[2]); acc = dp4(acc, w[3], xv[3]);
        smem[L_OUT5 + bb*76 + j5] = fmaxf(acc, 0.f);
      }
      __syncthreads();
      const int j = bx, bw = widx;
      float4 xq0 = (k0 < 76) ? *(const float4*)(smem + L_OUT5 + bw*76 + k0)
                             : ldg4(hQi + bw*228 + k0 - 76);
      float4 xq1; if (l < 12) xq1 = ldg4(hQi + bw*228 + 180 + k0);
      float4 xw0 = (l < 57) ? ldg4(F + F_OSIG + bw*228 + k0)
                            : ldg4(F + F_OUT3 + bw*228 + k0 - 228);
      float4 xw1; if (l < 50) xw1 = ldg4(F + F_OUT3 + bw*228 + 28 + k0);
      const float* qr = F + PQ + (size_t)j*304;
      const float* qz = qr + 225*304;
      const float* qn = qr + 450*304;
      const float* w4r = F + PW4 + (size_t)j*456;
      float4 wr0 = ldg4(qr + k0), wz0 = ldg4(qz + k0), wn0 = ldg4(qn + k0);
      float4 w40 = ldg4(w4r + k0);
      float ar=0.f, az=0.f, ani=0.f, anh=0.f, a4=0.f;
      ar = dp4(ar, wr0, xq0); az = dp4(az, wz0, xq0);
      { float tt = dp4(0.f, wn0, xq0); if (k0 < 76) ani += tt; else anh += tt; }
      a4 = dp4(a4, w40, xw0);
      if (l < 12) {
        float4 wr1 = ldg4(qr + 256 + k0), wz1 = ldg4(qz + 256 + k0), wn1 = ldg4(qn + 256 + k0);
        ar = dp4(ar, wr1, xq1); az = dp4(az, wz1, xq1); anh = dp4(anh, wn1, xq1);
      }
      if (l < 50) a4 = dp4(a4, ldg4(w4r + 256 + k0), xw1);
      ar = red64(ar); az = red64(az); ani = red64(ani); anh = red64(anh); a4 = red64(a4);
      if (l == 0) {
        float r = sigf(ar + a.bihQ[j] + a.bhhQ[j]);
        float z = sigf(az + a.bihQ[225+j] + a.bhhQ[225+j]);
        float n = tanhf(ani + a.bihQ[450+j] + r*(anh + a.bhhQ[450+j]));
        hQo[bw*228 + j] = (1.f - z)*n + z*hQi[bw*228 + j];
        if (t > 0) F[F_HSIG + bw*228 + j] = fmaxf(a4 + a.b4[j], 0.f);
      }
    }
    gbar(ib, ep); ++ep;

    // ==== B: out6(LDS) ; osig GRU (x=[hQ|out6], h=hSig) ====================
    if (bx < 225) {
      for (int i = tid; i < 1200; i += NTH) {
        int bb = i/75, j6 = i - bb*75;
        const float4* w  = (const float4*)(F + PW6 + j6*16);
        const float4* xv = (const float4*)(F + F_FWD + bb*16);
        float acc = a.b6[j6];
        acc = dp4(acc, w[0], xv[0]); acc = dp4(acc, w[1], xv[1]);
        acc = dp4(acc, w[2], xv[2]); acc = dp4(acc, w[3], xv[3]);
        smem[L_OUT6 + bb*76 + j6] = fmaxf(acc, 0.f);
      }
      __syncthreads();
      const int j = bx, bw = widx;
      float4 x0 = (l < 57) ? ldg4(hQo + bw*228 + k0)
                           : *(const float4*)(smem + L_OUT6 + bw*76 + k0 - 228);
      float4 x1 = (l < 12) ? *(const float4*)(smem + L_OUT6 + bw*76 + 28 + k0)
                           : ldg4(F + F_HSIG + bw*228 + k0 - 48);
      float4 x2; if (l < 5) x2 = ldg4(F + F_HSIG + bw*228 + 208 + k0);
      const float* gr = F + PSIG + (size_t)j*544;
      const float* gz = gr + 225*544;
      const float* gn = gr + 450*544;
      float4 wr0 = ldg4(gr + k0),     wz0 = ldg4(gz + k0),     wn0 = ldg4(gn + k0);
      float4 wr1 = ldg4(gr + 256+k0), wz1 = ldg4(gz + 256+k0), wn1 = ldg4(gn + 256+k0);
      float ar=0.f, az=0.f, ani=0.f, anh=0.f;
      ar = dp4(ar, wr0, x0); az = dp4(az, wz0, x0); ani = dp4(ani, wn0, x0);
      ar = dp4(ar, wr1, x1); az = dp4(az, wz1, x1);
      { float tt = dp4(0.f, wn1, x1); if (l < 12) ani += tt; else anh += tt; }
      if (l < 5) {
        float4 wr2 = ldg4(gr + 512+k0), wz2 = ldg4(gz + 512+k0), wn2 = ldg4(gn + 512+k0);
        ar = dp4(ar, wr2, x2); az = dp4(az, wz2, x2); anh = dp4(anh, wn2, x2);
      }
      ar = red64(ar); az = red64(az); ani = red64(ani); anh = red64(anh);
      if (l == 0) {
        float r = sigf(ar + a.bihSig[j] + a.bhhSig[j]);
        float z = sigf(az + a.bihSig[225+j] + a.bhhSig[225+j]);
        float n = tanhf(ani + a.bihSig[450+j] + r*(anh + a.bhhSig[450+j]));
        float val = (1.f - z)*n + z*F[F_HSIG + bw*228 + j];
        F[F_OSIG + bw*228 + j] = val;
        F[F_XV + bw*452 + j]   = val;
      }
    }
    gbar(ib, ep); ++ep;

    // ==== C: out1 = relu(W1 @ osig + b1) ===================================
    if (bx < 225) {
      const int j = bx, bw = widx;
      float acc = 0.f;
      if (l < 57) {
        float4 w0 = ldg4(F + PW1 + (size_t)j*228 + k0);
        float4 x0 = ldg4(F + F_OSIG + bw*228 + k0);
        acc = dp4(0.f, w0, x0);
      }
      acc = red64(acc);
      if (l == 0) F[F_OUT1 + bw*228 + j] = fmaxf(acc + a.b1[j], 0.f);
    }
    gbar(ib, ep); ++ep;

    // ==== D: out7(LDS) ; hS GRU (x=[out1|out7], h=hS) ======================
    if (bx < 225) {
      for (int i = tid; i < 2400; i += NTH) {
        int bb = i/150, j7 = i - bb*150;
        const float4* w  = (const float4*)(F + PW7 + j7*32);
        const float4* vo = (const float4*)(F + F_OBSD + bb*16);
        const float4* vd = (const float4*)(F + F_DY + bb*16);
        float acc = a.b7[j7];
        acc = dp4(acc, w[0], vo[0]); acc = dp4(acc, w[1], vo[1]);
        acc = dp4(acc, w[2], vo[2]); acc = dp4(acc, w[3], vo[3]);
        acc = dp4(acc, w[4], vd[0]); acc = dp4(acc, w[5], vd[1]);
        acc = dp4(acc, w[6], vd[2]); acc = dp4(acc, w[7], vd[3]);
        smem[L_OUT7 + bb*152 + j7] = fmaxf(acc, 0.f);
      }
      __syncthreads();
      const int j = bx, bw = widx;
      float4 x0 = (l < 57) ? ldg4(F + F_OUT1 + bw*228 + k0)
                           : *(const float4*)(smem + L_OUT7 + bw*152 + k0 - 228);
      float4 x1 = (l < 31) ? *(const float4*)(smem + L_OUT7 + bw*152 + 28 + k0)
                           : ldg4(hSi + bw*228 + k0 - 124);
      float4 x2; if (l < 24) x2 = ldg4(hSi + bw*228 + 132 + k0);
      const float* gr = F + PS + (size_t)j*608;
      const float* gz = gr + 225*608;
      const float* gn = gr + 450*608;
      float4 wr0 = ldg4(gr + k0),     wz0 = ldg4(gz + k0),     wn0 = ldg4(gn + k0);
      float4 wr1 = ldg4(gr + 256+k0), wz1 = ldg4(gz + 256+k0), wn1 = ldg4(gn + 256+k0);
      float ar=0.f, az=0.f, ani=0.f, anh=0.f;
      ar = dp4(ar, wr0, x0); az = dp4(az, wz0, x0); ani = dp4(ani, wn0, x0);
      ar = dp4(ar, wr1, x1); az = dp4(az, wz1, x1);
      { float tt = dp4(0.f, wn1, x1); if (l < 31) ani += tt; else anh += tt; }
      if (l < 24) {
        float4 wr2 = ldg4(gr + 512+k0), wz2 = ldg4(gz + 512+k0), wn2 = ldg4(gn + 512+k0);
        ar = dp4(ar, wr2, x2); az = dp4(az, wz2, x2); anh = dp4(anh, wn2, x2);
      }
      ar = red64(ar); az = red64(az); ani = red64(ani); anh = red64(anh);
      if (l == 0) {
        float r = sigf(ar + a.bihS[j] + a.bhhS[j]);
        float z = sigf(az + a.bihS[225+j] + a.bhhS[225+j]);
        float n = tanhf(ani + a.bihS[450+j] + r*(anh + a.bhhS[450+j]));
        float val = (1.f - z)*n + z*hSi[bw*228 + j];
        hSo[bw*228 + j]              = val;
        F[F_XV + bw*452 + 225 + j]   = val;
      }
    }
    gbar(ib, ep); ++ep;

    // ==== E: hid2 = relu(W2aP @ xv + b2a) — 2 rows x 16 b per wave =========
    {
      for (int i = tid; i < 7232; i += NTH) smem[L_XV + i] = F[F_XV + i];
      __syncthreads();
      if (bx < 250) {
        const int r0 = bx*72;
        for (int ps = 0; ps < 3; ++ps) {
          const int pi = ps*16 + widx;
          if (pi >= 36) break;
          const int rA = r0 + 2*pi;
          const float* wAp = F + W2AP + (size_t)rA*452;
          const float* wBp = wAp + 452;
          float aA[16], aB[16];
          #pragma unroll
          for (int i = 0; i < 16; ++i) { aA[i] = 0.f; aB[i] = 0.f; }
          {
            float4 wA = ldg4(wAp + k0), wB = ldg4(wBp + k0);
            #pragma unroll
            for (int bb = 0; bb < 16; ++bb) {
              float4 xv = *(const float4*)(smem + L_XV + bb*452 + k0);
              aA[bb] = dp4(aA[bb], wA, xv);
              aB[bb] = dp4(aB[bb], wB, xv);
            }
          }
          if (l < 49) {
            float4 wA = ldg4(wAp + 256 + k0), wB = ldg4(wBp + 256 + k0);
            #pragma unroll
            for (int bb = 0; bb < 16; ++bb) {
              float4 xv = *(const float4*)(smem + L_XV + bb*452 + 256 + k0);
              aA[bb] = dp4(aA[bb], wA, xv);
              aB[bb] = dp4(aB[bb], wB, xv);
            }
          }
          #pragma unroll
          for (int i = 0; i < 16; ++i) { aA[i] = red64(aA[i]); aB[i] = red64(aB[i]); }
          if (l == 0) {
            float bA = a.b2a[rA], bB = a.b2a[rA + 1];
            #pragma unroll
            for (int i = 0; i < 16; ++i) {
              F[F_HID2 + i*18000 + rA]     = fmaxf(aA[i] + bA, 0.f);
              F[F_HID2 + i*18000 + rA + 1] = fmaxf(aB[i] + bB, 0.f);
            }
          }
        }
      }
    }
    gbar(ib, ep); ++ep;

    // ==== F: W2b partials — 228 WGs: (jg=bx>>2, kq=bx&3), wave = b =========
    if (bx < 228) {
      const int jg = bx >> 2, kq = bx & 3, j0 = jg*4;
      const int nr = (jg == 56) ? 1 : 4;
      const float4* hb = (const float4*)(F + F_HID2 + (size_t)widx*18000) + kq*1125;
      const float4* w0 = (const float4*)a.W2b + (size_t)j0*4500 + kq*1125;
      const float4* w1 = (nr > 1) ? ((const float4*)a.W2b + (size_t)(j0+1)*4500 + kq*1125) : w0;
      const float4* w2 = (nr > 1) ? ((const float4*)a.W2b + (size_t)(j0+2)*4500 + kq*1125) : w0;
      const float4* w3 = (nr > 1) ? ((const float4*)a.W2b + (size_t)(j0+3)*4500 + kq*1125) : w0;
      float a0=0.f, a1=0.f, a2=0.f, a3=0.f;
      #pragma unroll 2
      for (int c = 0; c < 17; ++c) {
        int idx = c*64 + l;
        float4 h4 = hb[idx];
        float4 q0 = w0[idx], q1 = w1[idx], q2 = w2[idx], q3 = w3[idx];
        a0 = dp4(a0,q0,h4); a1 = dp4(a1,q1,h4); a2 = dp4(a2,q2,h4); a3 = dp4(a3,q3,h4);
      }
      if (l < 37) {
        int idx = 1088 + l;
        float4 h4 = hb[idx];
        float4 q0 = w0[idx], q1 = w1[idx], q2 = w2[idx], q3 = w3[idx];
        a0 = dp4(a0,q0,h4); a1 = dp4(a1,q1,h4); a2 = dp4(a2,q2,h4); a3 = dp4(a3,q3,h4);
      }
      a0 = red64(a0); a1 = red64(a1); a2 = red64(a2); a3 = red64(a3);
      if (l == 0) {
        float* pp = F + F_P2 + ((widx*228 + j0) << 2) + kq;
        pp[0] = a0;
        if (nr > 1) { pp[4] = a1; pp[8] = a2; pp[12] = a3; }
      }
    }
    gbar(ib, ep); ++ep;

    // ==== G: out2(LDS) ; out3 = relu(W3@[hS|out2]+b3) ; x update ===========
    if (bx < 225) {
      for (int i = tid; i < 3648; i += NTH) {
        int bb = i/228, j2 = i - bb*228;
        float v = 0.f;
        if (j2 < 225) {
          float4 pq = *(const float4*)(F + F_P2 + ((bb*228 + j2) << 2));
          v = pq.x + pq.y + pq.z + pq.w + a.b2b[j2];
        }
        smem[L_OUT2 + i] = v;
      }
      __syncthreads();
      const int j = bx, bw = widx;
      float4 x0 = (l < 57) ? ldg4(hSo + bw*228 + k0)
                           : *(const float4*)(smem + L_OUT2 + bw*228 + k0 - 228);
      float4 x1; if (l < 50) x1 = *(const float4*)(smem + L_OUT2 + bw*228 + 28 + k0);
      const float* w3r = F + PW3 + (size_t)j*456;
      float acc = dp4(0.f, ldg4(w3r + k0), x0);
      if (l < 50) acc = dp4(acc, ldg4(w3r + 256 + k0), x1);
      acc = red64(acc);
      if (l == 0) F[F_OUT3 + bw*228 + j] = fmaxf(acc + a.b3[j], 0.f);
    } else if (bx == 225) {
      for (int i = tid; i < 240; i += NTH) {
        int bb = i/15, jj = i - bb*15;
        float4 pq = *(const float4*)(F + F_P2 + ((bb*228 + jj) << 2));
        float o2 = pq.x + pq.y + pq.z + pq.w + a.b2b[jj];
        float xold = F[F_XP + i], dy = F[F_DY + bb*16 + jj];
        float xnew = fmaf(o2, dy, xold);
        a.out[t*240 + i] = xnew;
        F[F_XP + i] = xnew;
        if (t + 1 < TT) {
          float y1 = a.y[(t+1)*480 + bb*30 + jj];
          float y0 = a.y[t*480     + bb*30 + jj];
          F[F_DY   + bb*16 + jj] = y1 - xnew;
          F[F_OBSD + bb*16 + jj] = y1 - y0;
          F[F_FWD  + bb*16 + jj] = xnew - xold;
        }
      }
    }
    gbar(ib, ep); ++ep;
  }
}

extern "C" void kernel_launch(void* const* d_in, const int* in_sizes, int n_in,
                              void* d_out, int out_size, void* d_ws, size_t ws_size,
                              hipStream_t stream) {
  (void)in_sizes; (void)n_in; (void)out_size; (void)ws_size;
  KArgs a;
  int k = 0;
  a.y      = (const float*)d_in[k++];
  a.x0     = (const float*)d_in[k++];
  a.hQ0    = (const float*)d_in[k++];
  a.hSig0  = (const float*)d_in[k++];
  a.hS0    = (const float*)d_in[k++];
  a.WihQ   = (const float*)d_in[k++];
  a.WhhQ   = (const float*)d_in[k++];
  a.bihQ   = (const float*)d_in[k++];
  a.bhhQ   = (const float*)d_in[k++];
  a.WihSig = (const float*)d_in[k++];
  a.WhhSig = (const float*)d_in[k++];
  a.bihSig = (const float*)d_in[k++];
  a.bhhSig = (const float*)d_in[k++];
  a.WihS   = (const float*)d_in[k++];
  a.WhhS   = (const float*)d_in[k++];
  a.bihS   = (const float*)d_in[k++];
  a.bhhS   = (const float*)d_in[k++];
  a.W1  = (const float*)d_in[k++];  a.b1  = (const float*)d_in[k++];
  a.W2a = (const float*)d_in[k++];  a.b2a = (const float*)d_in[k++];
  a.W2b = (const float*)d_in[k++];  a.b2b = (const float*)d_in[k++];
  a.W3  = (const float*)d_in[k++];  a.b3  = (const float*)d_in[k++];
  a.W4  = (const float*)d_in[k++];  a.b4  = (const float*)d_in[k++];
  a.W5  = (const float*)d_in[k++];  a.b5  = (const float*)d_in[k++];
  a.W6  = (const float*)d_in[k++];  a.b6  = (const float*)d_in[k++];
  a.W7  = (const float*)d_in[k++];  a.b7  = (const float*)d_in[k++];
  a.out = (float*)d_out;
  a.ib  = (int*)d_ws;
  a.fb  = (float*)((char*)d_ws + INT_TOTAL*sizeof(int));

  hipLaunchKernelGGL(knet_init, dim3(2048), dim3(256), 0, stream, a);
  hipLaunchKernelGGL(knet_main, dim3(NWG), dim3(NTH), 0, stream, a);
}

// Round 5
// 47204.752 us; speedup vs baseline: 3.3127x; 1.0722x over previous
//
#include <hip/hip_runtime.h>
#include <math.h>

// ============================================================================
// KNet RNN — persistent kernel, round 5: decontended grid barrier.
// Identical compute to round 4. Barrier v2: 16 groups x 16 WGs, each group
// counter on its own 64B cache line (stride 16 ints), top counter on its own
// line; per-epoch stride 272 ints. 7 grid barriers/step.
// ============================================================================

#define NWG 256
#define NTH 1024
#define TT  256
#define NEPOCH 1792            // 7 * 256
#define EP_STRIDE 272          // 16 group lines (16 ints each) + 1 top line
#define OFF_GO   (NEPOCH*EP_STRIDE)
#define INT_TOTAL (OFF_GO + 16)

// float-region offsets
#define F_HQ    0         // [2][16][228]
#define F_HS    7296      // [2][16][228]
#define F_HSIG  14592     // [16][228]
#define F_XP    18240     // [240]
#define F_DY    18480     // [16][16]
#define F_FWD   18736     // [16][16]
#define F_OBSD  18992     // [16][16]
#define F_OSIG  19248     // [16][228]
#define F_OUT1  22896     // [16][228]
#define F_OUT3  26544     // [16][228]
#define F_XV    30192     // [16][452]  x for W2a: [b][osig|hS]
#define F_P2    37424     // [16][228][4]
#define F_HID2  52016     // [16][18000]
#define PQ      340016    // 675 x 304  [Wih 75 pad 76 | Whh 225 pad 228]
#define PSIG    545216    // 675 x 544
#define PS      912416    // 675 x 608
#define PW1     1322816   // 225 x 228
#define PW3     1374116   // 225 x 456
#define PW4     1476716   // 225 x 456
#define PW5     1579316   // 75 x 16
#define PW6     1580516   // 75 x 16
#define PW7     1581716   // 150 x 32
#define W2AP    1586516   // 18000 x 452

// LDS layout (floats)
#define L_OUT5 0
#define L_OUT6 1216
#define L_OUT7 2432
#define L_OUT2 4864
#define L_XV   0
#define L_TOTAL 8512

struct KArgs {
  const float *y,*x0,*hQ0,*hSig0,*hS0;
  const float *WihQ,*WhhQ,*bihQ,*bhhQ;
  const float *WihSig,*WhhSig,*bihSig,*bhhSig;
  const float *WihS,*WhhS,*bihS,*bhhS;
  const float *W1,*b1,*W2a,*b2a,*W2b,*b2b,*W3,*b3,*W4,*b4;
  const float *W5,*b5,*W6,*b6,*W7,*b7;
  float* out;
  int*   ib;
  float* fb;
};

__device__ __forceinline__ float sigf(float x) { return 1.0f/(1.0f + __expf(-x)); }
__device__ __forceinline__ float dp4(float acc, float4 w, float4 x) {
  acc = fmaf(w.x, x.x, acc); acc = fmaf(w.y, x.y, acc);
  acc = fmaf(w.z, x.z, acc); acc = fmaf(w.w, x.w, acc);
  return acc;
}
__device__ __forceinline__ float4 ldg4(const float* p){ return *(const float4*)p; }
__device__ __forceinline__ float red64(float v) {
  v += __shfl_xor(v, 1, 64);  v += __shfl_xor(v, 2, 64);
  v += __shfl_xor(v, 4, 64);  v += __shfl_xor(v, 8, 64);
  v += __shfl_xor(v, 16, 64); v += __shfl_xor(v, 32, 64);
  return v;
}

// Barrier v2: 16 groups of 16 WGs; group counters on separate 64B lines.
__device__ __forceinline__ void gbar(int* ib, int e) {
  __syncthreads();
  if (threadIdx.x == 0) {
    __threadfence();
    const int base = e * EP_STRIDE;
    const int g = (int)(blockIdx.x >> 4);
    int prev = __hip_atomic_fetch_add(ib + base + g*16, 1,
                                      __ATOMIC_ACQ_REL, __HIP_MEMORY_SCOPE_AGENT);
    if (prev == 15) {
      int pt = __hip_atomic_fetch_add(ib + base + 256, 1,
                                      __ATOMIC_ACQ_REL, __HIP_MEMORY_SCOPE_AGENT);
      if (pt == 15)
        __hip_atomic_store(ib + OFF_GO, e, __ATOMIC_RELEASE, __HIP_MEMORY_SCOPE_AGENT);
    }
    while (__hip_atomic_load(ib + OFF_GO, __ATOMIC_RELAXED, __HIP_MEMORY_SCOPE_AGENT) < e)
      __builtin_amdgcn_s_sleep(2);
    __threadfence();
  }
  __syncthreads();
}

__global__ void knet_init(KArgs a) {
  int gt = blockIdx.x*blockDim.x + threadIdx.x;
  int nt = gridDim.x*blockDim.x;
  float* F = a.fb;
  for (int i = gt; i < INT_TOTAL; i += nt) a.ib[i] = (i == OFF_GO) ? -1 : 0;
  for (int i = gt; i < 3648; i += nt) {
    int b = i/228, j = i - b*228;
    float hq=0.f, hs=0.f, hg=0.f;
    if (j < 225) { hq = a.hQ0[b*225+j]; hs = a.hS0[b*225+j]; hg = a.hSig0[b*225+j]; }
    F[F_HQ + i] = hq; F[F_HS + i] = hs; F[F_HSIG + i] = hg;
  }
  for (int i = gt; i < 240; i += nt) F[F_XP + i] = a.x0[i];
  for (int i = gt; i < 256; i += nt) {
    int b = i >> 4, j = i & 15;
    float dy=0.f, od=0.f;
    if (j < 15) {
      float ob = a.y[b*30 + j], xv = a.x0[b*15 + j];
      dy = ob - xv; od = ob - xv;
    }
    F[F_DY + i] = dy; F[F_OBSD + i] = od; F[F_FWD + i] = 0.f;
  }
  for (int i = gt; i < 675*304; i += nt) {
    int r = i/304, d = i - r*304; float v = 0.f;
    if (d < 75) v = a.WihQ[r*75 + d];
    else if (d >= 76 && d < 301) v = a.WhhQ[r*225 + d - 76];
    F[PQ + i] = v;
  }
  for (int i = gt; i < 675*544; i += nt) {
    int r = i/544, d = i - r*544; float v = 0.f;
    if (d < 225) v = a.WihSig[r*300 + d];
    else if (d >= 228 && d < 303) v = a.WihSig[r*300 + 225 + d - 228];
    else if (d >= 304 && d < 529) v = a.WhhSig[r*225 + d - 304];
    F[PSIG + i] = v;
  }
  for (int i = gt; i < 675*608; i += nt) {
    int r = i/608, d = i - r*608; float v = 0.f;
    if (d < 225) v = a.WihS[r*375 + d];
    else if (d >= 228 && d < 378) v = a.WihS[r*375 + 225 + d - 228];
    else if (d >= 380 && d < 605) v = a.WhhS[r*225 + d - 380];
    F[PS + i] = v;
  }
  for (int i = gt; i < 225*228; i += nt) {
    int r = i/228, d = i - r*228;
    F[PW1 + i] = (d < 225) ? a.W1[r*225 + d] : 0.f;
  }
  for (int i = gt; i < 225*456; i += nt) {
    int r = i/456, d = i - r*456; float v3 = 0.f, v4 = 0.f;
    if (d < 225)               { v3 = a.W3[r*450 + d];           v4 = a.W4[r*450 + d]; }
    else if (d >= 228 && d < 453) { v3 = a.W3[r*450 + 225 + d - 228]; v4 = a.W4[r*450 + 225 + d - 228]; }
    F[PW3 + i] = v3; F[PW4 + i] = v4;
  }
  for (int i = gt; i < 75*16; i += nt) {
    int r = i >> 4, d = i & 15;
    F[PW5 + i] = (d < 15) ? a.W5[r*15 + d] : 0.f;
    F[PW6 + i] = (d < 15) ? a.W6[r*15 + d] : 0.f;
  }
  for (int i = gt; i < 150*32; i += nt) {
    int r = i >> 5, d = i & 31; float v = 0.f;
    if (d < 15) v = a.W7[r*30 + d];
    else if (d >= 16 && d < 31) v = a.W7[r*30 + 15 + d - 16];
    F[PW7 + i] = v;
  }
  for (long long i = gt; i < 18000LL*452; i += nt) {
    long long r = i/452; int d = (int)(i - r*452);
    F[W2AP + i] = (d < 450) ? a.W2a[r*450 + d] : 0.f;
  }
}

__global__ __launch_bounds__(NTH, 4) void knet_main(KArgs a) {
  __shared__ float smem[L_TOTAL];
  const int tid  = threadIdx.x;
  const int widx = tid >> 6;
  const int l    = tid & 63;
  const int bx   = (int)blockIdx.x;
  const int k0   = l*4;
  float* F  = a.fb;
  int*   ib = a.ib;
  int ep = 0;

  for (int t = 0; t < TT; ++t) {
    const int p = t & 1, q = p ^ 1;
    float* hQi = F + F_HQ + p*3648;  float* hQo = F + F_HQ + q*3648;
    float* hSi = F + F_HS + p*3648;  float* hSo = F + F_HS + q*3648;

    // ==== A: out5(LDS) ; hQ GRU ; hSig = out4(prev osig,out3) ==============
    if (bx < 225) {
      for (int i = tid; i < 1200; i += NTH) {
        int bb = i/75, j5 = i - bb*75;
        const float4* w  = (const float4*)(F + PW5 + j5*16);
        const float4* xv = (const float4*)(F + F_FWD + bb*16);
        float acc = a.b5[j5];
        acc = dp4(acc, w[0], xv[0]); acc = dp4(acc, w[1], xv[1]);
        acc = dp4(acc, w[2], xv[2]); acc = dp4(acc, w[3], xv[3]);
        smem[L_OUT5 + bb*76 + j5] = fmaxf(acc, 0.f);
      }
      __syncthreads();
      const int j = bx, bw = widx;
      float4 xq0 = (k0 < 76) ? *(const float4*)(smem + L_OUT5 + bw*76 + k0)
                             : ldg4(hQi + bw*228 + k0 - 76);
      float4 xq1; if (l < 12) xq1 = ldg4(hQi + bw*228 + 180 + k0);
      float4 xw0 = (l < 57) ? ldg4(F + F_OSIG + bw*228 + k0)
                            : ldg4(F + F_OUT3 + bw*228 + k0 - 228);
      float4 xw1; if (l < 50) xw1 = ldg4(F + F_OUT3 + bw*228 + 28 + k0);
      const float* qr = F + PQ + (size_t)j*304;
      const float* qz = qr + 225*304;
      const float* qn = qr + 450*304;
      const float* w4r = F + PW4 + (size_t)j*456;
      float4 wr0 = ldg4(qr + k0), wz0 = ldg4(qz + k0), wn0 = ldg4(qn + k0);
      float4 w40 = ldg4(w4r + k0);
      float ar=0.f, az=0.f, ani=0.f, anh=0.f, a4=0.f;
      ar = dp4(ar, wr0, xq0); az = dp4(az, wz0, xq0);
      { float tt = dp4(0.f, wn0, xq0); if (k0 < 76) ani += tt; else anh += tt; }
      a4 = dp4(a4, w40, xw0);
      if (l < 12) {
        float4 wr1 = ldg4(qr + 256 + k0), wz1 = ldg4(qz + 256 + k0), wn1 = ldg4(qn + 256 + k0);
        ar = dp4(ar, wr1, xq1); az = dp4(az, wz1, xq1); anh = dp4(anh, wn1, xq1);
      }
      if (l < 50) a4 = dp4(a4, ldg4(w4r + 256 + k0), xw1);
      ar = red64(ar); az = red64(az); ani = red64(ani); anh = red64(anh); a4 = red64(a4);
      if (l == 0) {
        float r = sigf(ar + a.bihQ[j] + a.bhhQ[j]);
        float z = sigf(az + a.bihQ[225+j] + a.bhhQ[225+j]);
        float n = tanhf(ani + a.bihQ[450+j] + r*(anh + a.bhhQ[450+j]));
        hQo[bw*228 + j] = (1.f - z)*n + z*hQi[bw*228 + j];
        if (t > 0) F[F_HSIG + bw*228 + j] = fmaxf(a4 + a.b4[j], 0.f);
      }
    }
    gbar(ib, ep); ++ep;

    // ==== B: out6(LDS) ; osig GRU (x=[hQ|out6], h=hSig) ====================
    if (bx < 225) {
      for (int i = tid; i < 1200; i += NTH) {
        int bb = i/75, j6 = i - bb*75;
        const float4* w  = (const float4*)(F + PW6 + j6*16);
        const float4* xv = (const float4*)(F + F_FWD + bb*16);
        float acc = a.b6[j6];
        acc = dp4(acc, w[0], xv[0]); acc = dp4(acc, w[1], xv[1]);
        acc = dp4(acc, w[2], xv[2]); acc = dp4(acc, w[3], xv[3]);
        smem[L_OUT6 + bb*76 + j6] = fmaxf(acc, 0.f);
      }
      __syncthreads();
      const int j = bx, bw = widx;
      float4 x0 = (l < 57) ? ldg4(hQo + bw*228 + k0)
                           : *(const float4*)(smem + L_OUT6 + bw*76 + k0 - 228);
      float4 x1 = (l < 12) ? *(const float4*)(smem + L_OUT6 + bw*76 + 28 + k0)
                           : ldg4(F + F_HSIG + bw*228 + k0 - 48);
      float4 x2; if (l < 5) x2 = ldg4(F + F_HSIG + bw*228 + 208 + k0);
      const float* gr = F + PSIG + (size_t)j*544;
      const float* gz = gr + 225*544;
      const float* gn = gr + 450*544;
      float4 wr0 = ldg4(gr + k0),     wz0 = ldg4(gz + k0),     wn0 = ldg4(gn + k0);
      float4 wr1 = ldg4(gr + 256+k0), wz1 = ldg4(gz + 256+k0), wn1 = ldg4(gn + 256+k0);
      float ar=0.f, az=0.f, ani=0.f, anh=0.f;
      ar = dp4(ar, wr0, x0); az = dp4(az, wz0, x0); ani = dp4(ani, wn0, x0);
      ar = dp4(ar, wr1, x1); az = dp4(az, wz1, x1);
      { float tt = dp4(0.f, wn1, x1); if (l < 12) ani += tt; else anh += tt; }
      if (l < 5) {
        float4 wr2 = ldg4(gr + 512+k0), wz2 = ldg4(gz + 512+k0), wn2 = ldg4(gn + 512+k0);
        ar = dp4(ar, wr2, x2); az = dp4(az, wz2, x2); anh = dp4(anh, wn2, x2);
      }
      ar = red64(ar); az = red64(az); ani = red64(ani); anh = red64(anh);
      if (l == 0) {
        float r = sigf(ar + a.bihSig[j] + a.bhhSig[j]);
        float z = sigf(az + a.bihSig[225+j] + a.bhhSig[225+j]);
        float n = tanhf(ani + a.bihSig[450+j] + r*(anh + a.bhhSig[450+j]));
        float val = (1.f - z)*n + z*F[F_HSIG + bw*228 + j];
        F[F_OSIG + bw*228 + j] = val;
        F[F_XV + bw*452 + j]   = val;
      }
    }
    gbar(ib, ep); ++ep;

    // ==== C: out1 = relu(W1 @ osig + b1) ===================================
    if (bx < 225) {
      const int j = bx, bw = widx;
      float acc = 0.f;
      if (l < 57) {
        float4 w0 = ldg4(F + PW1 + (size_t)j*228 + k0);
        float4 x0 = ldg4(F + F_OSIG + bw*228 + k0);
        acc = dp4(0.f, w0, x0);
      }
      acc = red64(acc);
      if (l == 0) F[F_OUT1 + bw*228 + j] = fmaxf(acc + a.b1[j], 0.f);
    }
    gbar(ib, ep); ++ep;

    // ==== D: out7(LDS) ; hS GRU (x=[out1|out7], h=hS) ======================
    if (bx < 225) {
      for (int i = tid; i < 2400; i += NTH) {
        int bb = i/150, j7 = i - bb*150;
        const float4* w  = (const float4*)(F + PW7 + j7*32);
        const float4* vo = (const float4*)(F + F_OBSD + bb*16);
        const float4* vd = (const float4*)(F + F_DY + bb*16);
        float acc = a.b7[j7];
        acc = dp4(acc, w[0], vo[0]); acc = dp4(acc, w[1], vo[1]);
        acc = dp4(acc, w[2], vo[2]); acc = dp4(acc, w[3], vo[3]);
        acc = dp4(acc, w[4], vd[0]); acc = dp4(acc, w[5], vd[1]);
        acc = dp4(acc, w[6], vd[2]); acc = dp4(acc, w[7], vd[3]);
        smem[L_OUT7 + bb*152 + j7] = fmaxf(acc, 0.f);
      }
      __syncthreads();
      const int j = bx, bw = widx;
      float4 x0 = (l < 57) ? ldg4(F + F_OUT1 + bw*228 + k0)
                           : *(const float4*)(smem + L_OUT7 + bw*152 + k0 - 228);
      float4 x1 = (l < 31) ? *(const float4*)(smem + L_OUT7 + bw*152 + 28 + k0)
                           : ldg4(hSi + bw*228 + k0 - 124);
      float4 x2; if (l < 24) x2 = ldg4(hSi + bw*228 + 132 + k0);
      const float* gr = F + PS + (size_t)j*608;
      const float* gz = gr + 225*608;
      const float* gn = gr + 450*608;
      float4 wr0 = ldg4(gr + k0),     wz0 = ldg4(gz + k0),     wn0 = ldg4(gn + k0);
      float4 wr1 = ldg4(gr + 256+k0), wz1 = ldg4(gz + 256+k0), wn1 = ldg4(gn + 256+k0);
      float ar=0.f, az=0.f, ani=0.f, anh=0.f;
      ar = dp4(ar, wr0, x0); az = dp4(az, wz0, x0); ani = dp4(ani, wn0, x0);
      ar = dp4(ar, wr1, x1); az = dp4(az, wz1, x1);
      { float tt = dp4(0.f, wn1, x1); if (l < 31) ani += tt; else anh += tt; }
      if (l < 24) {
        float4 wr2 = ldg4(gr + 512+k0), wz2 = ldg4(gz + 512+k0), wn2 = ldg4(gn + 512+k0);
        ar = dp4(ar, wr2, x2); az = dp4(az, wz2, x2); anh = dp4(anh, wn2, x2);
      }
      ar = red64(ar); az = red64(az); ani = red64(ani); anh = red64(anh);
      if (l == 0) {
        float r = sigf(ar + a.bihS[j] + a.bhhS[j]);
        float z = sigf(az + a.bihS[225+j] + a.bhhS[225+j]);
        float n = tanhf(ani + a.bihS[450+j] + r*(anh + a.bhhS[450+j]));
        float val = (1.f - z)*n + z*hSi[bw*228 + j];
        hSo[bw*228 + j]              = val;
        F[F_XV + bw*452 + 225 + j]   = val;
      }
    }
    gbar(ib, ep); ++ep;

    // ==== E: hid2 = relu(W2aP @ xv + b2a) — 2 rows x 16 b per wave =========
    {
      for (int i = tid; i < 7232; i += NTH) smem[L_XV + i] = F[F_XV + i];
      __syncthreads();
      if (bx < 250) {
        const int r0 = bx*72;
        for (int ps = 0; ps < 3; ++ps) {
          const int pi = ps*16 + widx;
          if (pi >= 36) break;
          const int rA = r0 + 2*pi;
          const float* wAp = F + W2AP + (size_t)rA*452;
          const float* wBp = wAp + 452;
          float aA[16], aB[16];
          #pragma unroll
          for (int i = 0; i < 16; ++i) { aA[i] = 0.f; aB[i] = 0.f; }
          {
            float4 wA = ldg4(wAp + k0), wB = ldg4(wBp + k0);
            #pragma unroll
            for (int bb = 0; bb < 16; ++bb) {
              float4 xv = *(const float4*)(smem + L_XV + bb*452 + k0);
              aA[bb] = dp4(aA[bb], wA, xv);
              aB[bb] = dp4(aB[bb], wB, xv);
            }
          }
          if (l < 49) {
            float4 wA = ldg4(wAp + 256 + k0), wB = ldg4(wBp + 256 + k0);
            #pragma unroll
            for (int bb = 0; bb < 16; ++bb) {
              float4 xv = *(const float4*)(smem + L_XV + bb*452 + 256 + k0);
              aA[bb] = dp4(aA[bb], wA, xv);
              aB[bb] = dp4(aB[bb], wB, xv);
            }
          }
          #pragma unroll
          for (int i = 0; i < 16; ++i) { aA[i] = red64(aA[i]); aB[i] = red64(aB[i]); }
          if (l == 0) {
            float bA = a.b2a[rA], bB = a.b2a[rA + 1];
            #pragma unroll
            for (int i = 0; i < 16; ++i) {
              F[F_HID2 + i*18000 + rA]     = fmaxf(aA[i] + bA, 0.f);
              F[F_HID2 + i*18000 + rA + 1] = fmaxf(aB[i] + bB, 0.f);
            }
          }
        }
      }
    }
    gbar(ib, ep); ++ep;

    // ==== F: W2b partials — 228 WGs: (jg=bx>>2, kq=bx&3), wave = b =========
    if (bx < 228) {
      const int jg = bx >> 2, kq = bx & 3, j0 = jg*4;
      const int nr = (jg == 56) ? 1 : 4;
      const float4* hb = (const float4*)(F + F_HID2 + (size_t)widx*18000) + kq*1125;
      const float4* w0 = (const float4*)a.W2b + (size_t)j0*4500 + kq*1125;
      const float4* w1 = (nr > 1) ? ((const float4*)a.W2b + (size_t)(j0+1)*4500 + kq*1125) : w0;
      const float4* w2 = (nr > 1) ? ((const float4*)a.W2b + (size_t)(j0+2)*4500 + kq*1125) : w0;
      const float4* w3 = (nr > 1) ? ((const float4*)a.W2b + (size_t)(j0+3)*4500 + kq*1125) : w0;
      float a0=0.f, a1=0.f, a2=0.f, a3=0.f;
      #pragma unroll 2
      for (int c = 0; c < 17; ++c) {
        int idx = c*64 + l;
        float4 h4 = hb[idx];
        float4 q0 = w0[idx], q1 = w1[idx], q2 = w2[idx], q3 = w3[idx];
        a0 = dp4(a0,q0,h4); a1 = dp4(a1,q1,h4); a2 = dp4(a2,q2,h4); a3 = dp4(a3,q3,h4);
      }
      if (l < 37) {
        int idx = 1088 + l;
        float4 h4 = hb[idx];
        float4 q0 = w0[idx], q1 = w1[idx], q2 = w2[idx], q3 = w3[idx];
        a0 = dp4(a0,q0,h4); a1 = dp4(a1,q1,h4); a2 = dp4(a2,q2,h4); a3 = dp4(a3,q3,h4);
      }
      a0 = red64(a0); a1 = red64(a1); a2 = red64(a2); a3 = red64(a3);
      if (l == 0) {
        float* pp = F + F_P2 + ((widx*228 + j0) << 2) + kq;
        pp[0] = a0;
        if (nr > 1) { pp[4] = a1; pp[8] = a2; pp[12] = a3; }
      }
    }
    gbar(ib, ep); ++ep;

    // ==== G: out2(LDS) ; out3 = relu(W3@[hS|out2]+b3) ; x update ===========
    if (bx < 225) {
      for (int i = tid; i < 3648; i += NTH) {
        int bb = i/228, j2 = i - bb*228;
        float v = 0.f;
        if (j2 < 225) {
          float4 pq = *(const float4*)(F + F_P2 + ((bb*228 + j2) << 2));
          v = pq.x + pq.y + pq.z + pq.w + a.b2b[j2];
        }
        smem[L_OUT2 + i] = v;
      }
      __syncthreads();
      const int j = bx, bw = widx;
      float4 x0 = (l < 57) ? ldg4(hSo + bw*228 + k0)
                           : *(const float4*)(smem + L_OUT2 + bw*228 + k0 - 228);
      float4 x1; if (l < 50) x1 = *(const float4*)(smem + L_OUT2 + bw*228 + 28 + k0);
      const float* w3r = F + PW3 + (size_t)j*456;
      float acc = dp4(0.f, ldg4(w3r + k0), x0);
      if (l < 50) acc = dp4(acc, ldg4(w3r + 256 + k0), x1);
      acc = red64(acc);
      if (l == 0) F[F_OUT3 + bw*228 + j] = fmaxf(acc + a.b3[j], 0.f);
    } else if (bx == 225) {
      for (int i = tid; i < 240; i += NTH) {
        int bb = i/15, jj = i - bb*15;
        float4 pq = *(const float4*)(F + F_P2 + ((bb*228 + jj) << 2));
        float o2 = pq.x + pq.y + pq.z + pq.w + a.b2b[jj];
        float xold = F[F_XP + i], dy = F[F_DY + bb*16 + jj];
        float xnew = fmaf(o2, dy, xold);
        a.out[t*240 + i] = xnew;
        F[F_XP + i] = xnew;
        if (t + 1 < TT) {
          float y1 = a.y[(t+1)*480 + bb*30 + jj];
          float y0 = a.y[t*480     + bb*30 + jj];
          F[F_DY   + bb*16 + jj] = y1 - xnew;
          F[F_OBSD + bb*16 + jj] = y1 - y0;
          F[F_FWD  + bb*16 + jj] = xnew - xold;
        }
      }
    }
    gbar(ib, ep); ++ep;
  }
}

extern "C" void kernel_launch(void* const* d_in, const int* in_sizes, int n_in,
                              void* d_out, int out_size, void* d_ws, size_t ws_size,
                              hipStream_t stream) {
  (void)in_sizes; (void)n_in; (void)out_size; (void)ws_size;
  KArgs a;
  int k = 0;
  a.y      = (const float*)d_in[k++];
  a.x0     = (const float*)d_in[k++];
  a.hQ0    = (const float*)d_in[k++];
  a.hSig0  = (const float*)d_in[k++];
  a.hS0    = (const float*)d_in[k++];
  a.WihQ   = (const float*)d_in[k++];
  a.WhhQ   = (const float*)d_in[k++];
  a.bihQ   = (const float*)d_in[k++];
  a.bhhQ   = (const float*)d_in[k++];
  a.WihSig = (const float*)d_in[k++];
  a.WhhSig = (const float*)d_in[k++];
  a.bihSig = (const float*)d_in[k++];
  a.bhhSig = (const float*)d_in[k++];
  a.WihS   = (const float*)d_in[k++];
  a.WhhS   = (const float*)d_in[k++];
  a.bihS   = (const float*)d_in[k++];
  a.bhhS   = (const float*)d_in[k++];
  a.W1  = (const float*)d_in[k++];  a.b1  = (const float*)d_in[k++];
  a.W2a = (const float*)d_in[k++];  a.b2a = (const float*)d_in[k++];
  a.W2b = (const float*)d_in[k++];  a.b2b = (const float*)d_in[k++];
  a.W3  = (const float*)d_in[k++];  a.b3  = (const float*)d_in[k++];
  a.W4  = (const float*)d_in[k++];  a.b4  = (const float*)d_in[k++];
  a.W5  = (const float*)d_in[k++];  a.b5  = (const float*)d_in[k++];
  a.W6  = (const float*)d_in[k++];  a.b6  = (const float*)d_in[k++];
  a.W7  = (const float*)d_in[k++];  a.b7  = (const float*)d_in[k++];
  a.out = (float*)d_out;
  a.ib  = (int*)d_ws;
  a.fb  = (float*)((char*)d_ws + (size_t)INT_TOTAL*sizeof(int));

  hipLaunchKernelGGL(knet_init, dim3(2048), dim3(256), 0, stream, a);
  hipLaunchKernelGGL(knet_main, dim3(NWG), dim3(NTH), 0, stream, a);
}

// Round 7
// 34152.499 us; speedup vs baseline: 4.5787x; 1.3822x over previous
//
#include <hip/hip_runtime.h>
#include <math.h>

// ============================================================================
// KNet RNN — persistent kernel, round 6b: fence-free coherence model.
// (round 6 with the nontemporal-load compile fix: native clang vector type)
//   - communicated data via RELAXED agent-scope atomics (sc-bypass to LLC)
//   - barrier = relaxed atomics + per-thread s_waitcnt(0) drain
//   - read-only weights stay plain cached loads -> L1/L2-resident across steps
//   - W2b loads non-temporal to keep W2AP L2-resident
// ============================================================================

#define NWG 256
#define NTH 1024
#define TT  256
#define NEPOCH 1792            // 7 * 256
#define EP_STRIDE 272          // 16 group lines (16 ints) + 1 top line
#define OFF_GO   (NEPOCH*EP_STRIDE)
#define INT_TOTAL (OFF_GO + 16)

// float-region offsets
#define F_HQ    0         // [2][16][228]
#define F_HS    7296      // [2][16][228]
#define F_HSIG  14592     // [16][228]
#define F_XP    18240     // [240]
#define F_DY    18480     // [16][16]
#define F_FWD   18736     // [16][16]
#define F_OBSD  18992     // [16][16]
#define F_OSIG  19248     // [16][228]
#define F_OUT1  22896     // [16][228]
#define F_OUT3  26544     // [16][228]
#define F_XV    30192     // [16][452]
#define F_P2    37424     // [16][228][4]
#define F_HID2  52016     // [16][18000]
#define PQ      340016    // 675 x 304
#define PSIG    545216    // 675 x 544
#define PS      912416    // 675 x 608
#define PW1     1322816   // 225 x 228
#define PW3     1374116   // 225 x 456
#define PW4     1476716   // 225 x 456
#define PW5     1579316   // 75 x 16
#define PW6     1580516   // 75 x 16
#define PW7     1581716   // 150 x 32
#define W2AP    1586516   // 18000 x 452

// LDS layout (floats)
#define L_OUT5 0
#define L_OUT6 1216
#define L_OUT7 2432
#define L_OUT2 4864
#define L_XV   0
#define L_SCR  8512       // 512: FWD (A/B) or OBSD|DY (D)
#define L_TOTAL 9024

typedef float v4f __attribute__((ext_vector_type(4)));

struct KArgs {
  const float *y,*x0,*hQ0,*hSig0,*hS0;
  const float *WihQ,*WhhQ,*bihQ,*bhhQ;
  const float *WihSig,*WhhSig,*bihSig,*bhhSig;
  const float *WihS,*WhhS,*bihS,*bhhS;
  const float *W1,*b1,*W2a,*b2a,*W2b,*b2b,*W3,*b3,*W4,*b4;
  const float *W5,*b5,*W6,*b6,*W7,*b7;
  float* out;
  int*   ib;
  float* fb;
};

__device__ __forceinline__ float sigf(float x) { return 1.0f/(1.0f + __expf(-x)); }
__device__ __forceinline__ float dp4(float acc, float4 w, float4 x) {
  acc = fmaf(w.x, x.x, acc); acc = fmaf(w.y, x.y, acc);
  acc = fmaf(w.z, x.z, acc); acc = fmaf(w.w, x.w, acc);
  return acc;
}
__device__ __forceinline__ float4 ldg4(const float* p){ return *(const float4*)p; }
__device__ __forceinline__ float4 ldg4nt(const float4* p){
  v4f r = __builtin_nontemporal_load((const v4f*)p);
  float4 o; o.x = r.x; o.y = r.y; o.z = r.z; o.w = r.w; return o;
}

// coherent (sc-bypass) accessors for cross-WG communicated data
__device__ __forceinline__ float ald(const float* p) {
  return __hip_atomic_load(p, __ATOMIC_RELAXED, __HIP_MEMORY_SCOPE_AGENT);
}
__device__ __forceinline__ float4 ald4(const float* p) {
  float4 r; r.x=ald(p); r.y=ald(p+1); r.z=ald(p+2); r.w=ald(p+3); return r;
}
__device__ __forceinline__ void ast(float* p, float v) {
  __hip_atomic_store(p, v, __ATOMIC_RELAXED, __HIP_MEMORY_SCOPE_AGENT);
}

__device__ __forceinline__ float red64(float v) {
  v += __shfl_xor(v, 1, 64);  v += __shfl_xor(v, 2, 64);
  v += __shfl_xor(v, 4, 64);  v += __shfl_xor(v, 8, 64);
  v += __shfl_xor(v, 16, 64); v += __shfl_xor(v, 32, 64);
  return v;
}

// Fence-free barrier: every thread drains its own sc-stores (vmcnt 0), then
// thread 0 does relaxed arrival; control deps order group->top->GO.
__device__ __forceinline__ void gbar(int* ib, int e) {
  __builtin_amdgcn_s_waitcnt(0);
  __syncthreads();
  if (threadIdx.x == 0) {
    const int base = e * EP_STRIDE;
    const int g = (int)(blockIdx.x >> 4);
    int prev = __hip_atomic_fetch_add(ib + base + g*16, 1,
                                      __ATOMIC_RELAXED, __HIP_MEMORY_SCOPE_AGENT);
    if (prev == 15) {
      int pt = __hip_atomic_fetch_add(ib + base + 256, 1,
                                      __ATOMIC_RELAXED, __HIP_MEMORY_SCOPE_AGENT);
      if (pt == 15)
        __hip_atomic_store(ib + OFF_GO, e, __ATOMIC_RELAXED, __HIP_MEMORY_SCOPE_AGENT);
    }
    while (__hip_atomic_load(ib + OFF_GO, __ATOMIC_RELAXED, __HIP_MEMORY_SCOPE_AGENT) < e)
      __builtin_amdgcn_s_sleep(2);
  }
  __syncthreads();
}

__global__ void knet_init(KArgs a) {
  int gt = blockIdx.x*blockDim.x + threadIdx.x;
  int nt = gridDim.x*blockDim.x;
  float* F = a.fb;
  for (int i = gt; i < INT_TOTAL; i += nt) a.ib[i] = (i == OFF_GO) ? -1 : 0;
  for (int i = gt; i < 3648; i += nt) {
    int b = i/228, j = i - b*228;
    float hq=0.f, hs=0.f, hg=0.f;
    if (j < 225) { hq = a.hQ0[b*225+j]; hs = a.hS0[b*225+j]; hg = a.hSig0[b*225+j]; }
    F[F_HQ + i] = hq; F[F_HS + i] = hs; F[F_HSIG + i] = hg;
  }
  for (int i = gt; i < 7232; i += nt) F[F_XV + i] = 0.f;
  for (int i = gt; i < 240; i += nt) F[F_XP + i] = a.x0[i];
  for (int i = gt; i < 256; i += nt) {
    int b = i >> 4, j = i & 15;
    float dy=0.f, od=0.f;
    if (j < 15) {
      float ob = a.y[b*30 + j], xv = a.x0[b*15 + j];
      dy = ob - xv; od = ob - xv;
    }
    F[F_DY + i] = dy; F[F_OBSD + i] = od; F[F_FWD + i] = 0.f;
  }
  for (int i = gt; i < 675*304; i += nt) {
    int r = i/304, d = i - r*304; float v = 0.f;
    if (d < 75) v = a.WihQ[r*75 + d];
    else if (d >= 76 && d < 301) v = a.WhhQ[r*225 + d - 76];
    F[PQ + i] = v;
  }
  for (int i = gt; i < 675*544; i += nt) {
    int r = i/544, d = i - r*544; float v = 0.f;
    if (d < 225) v = a.WihSig[r*300 + d];
    else if (d >= 228 && d < 303) v = a.WihSig[r*300 + 225 + d - 228];
    else if (d >= 304 && d < 529) v = a.WhhSig[r*225 + d - 304];
    F[PSIG + i] = v;
  }
  for (int i = gt; i < 675*608; i += nt) {
    int r = i/608, d = i - r*608; float v = 0.f;
    if (d < 225) v = a.WihS[r*375 + d];
    else if (d >= 228 && d < 378) v = a.WihS[r*375 + 225 + d - 228];
    else if (d >= 380 && d < 605) v = a.WhhS[r*225 + d - 380];
    F[PS + i] = v;
  }
  for (int i = gt; i < 225*228; i += nt) {
    int r = i/228, d = i - r*228;
    F[PW1 + i] = (d < 225) ? a.W1[r*225 + d] : 0.f;
  }
  for (int i = gt; i < 225*456; i += nt) {
    int r = i/456, d = i - r*456; float v3 = 0.f, v4 = 0.f;
    if (d < 225)               { v3 = a.W3[r*450 + d];           v4 = a.W4[r*450 + d]; }
    else if (d >= 228 && d < 453) { v3 = a.W3[r*450 + 225 + d - 228]; v4 = a.W4[r*450 + 225 + d - 228]; }
    F[PW3 + i] = v3; F[PW4 + i] = v4;
  }
  for (int i = gt; i < 75*16; i += nt) {
    int r = i >> 4, d = i & 15;
    F[PW5 + i] = (d < 15) ? a.W5[r*15 + d] : 0.f;
    F[PW6 + i] = (d < 15) ? a.W6[r*15 + d] : 0.f;
  }
  for (int i = gt; i < 150*32; i += nt) {
    int r = i >> 5, d = i & 31; float v = 0.f;
    if (d < 15) v = a.W7[r*30 + d];
    else if (d >= 16 && d < 31) v = a.W7[r*30 + 15 + d - 16];
    F[PW7 + i] = v;
  }
  for (long long i = gt; i < 18000LL*452; i += nt) {
    long long r = i/452; int d = (int)(i - r*452);
    F[W2AP + i] = (d < 450) ? a.W2a[r*450 + d] : 0.f;
  }
}

__global__ __launch_bounds__(NTH, 4) void knet_main(KArgs a) {
  __shared__ float smem[L_TOTAL];
  const int tid  = threadIdx.x;
  const int widx = tid >> 6;
  const int l    = tid & 63;
  const int bx   = (int)blockIdx.x;
  const int k0   = l*4;
  float* F  = a.fb;
  int*   ib = a.ib;
  int ep = 0;

  for (int t = 0; t < TT; ++t) {
    const int p = t & 1, q = p ^ 1;
    float* hQi = F + F_HQ + p*3648;  float* hQo = F + F_HQ + q*3648;
    float* hSi = F + F_HS + p*3648;  float* hSo = F + F_HS + q*3648;

    // ==== A: out5(LDS) ; hQ GRU ; hSig = out4(prev osig,out3) ==============
    if (bx < 225) {
      if (tid < 256) smem[L_SCR + tid] = ald(F + F_FWD + tid);   // FWD -> LDS
      __syncthreads();
      for (int i = tid; i < 1200; i += NTH) {
        int bb = i/75, j5 = i - bb*75;
        const float4* w  = (const float4*)(F + PW5 + j5*16);
        const float4* xv = (const float4*)(smem + L_SCR + bb*16);
        float acc = a.b5[j5];
        acc = dp4(acc, w[0], xv[0]); acc = dp4(acc, w[1], xv[1]);
        acc = dp4(acc, w[2], xv[2]); acc = dp4(acc, w[3], xv[3]);
        smem[L_OUT5 + bb*76 + j5] = fmaxf(acc, 0.f);
      }
      __syncthreads();
      const int j = bx, bw = widx;
      float4 xq0 = (k0 < 76) ? *(const float4*)(smem + L_OUT5 + bw*76 + k0)
                             : ald4(hQi + bw*228 + k0 - 76);
      float4 xq1; if (l < 12) xq1 = ald4(hQi + bw*228 + 180 + k0);
      float4 xw0 = (l < 57) ? ald4(F + F_OSIG + bw*228 + k0)
                            : ald4(F + F_OUT3 + bw*228 + k0 - 228);
      float4 xw1; if (l < 50) xw1 = ald4(F + F_OUT3 + bw*228 + 28 + k0);
      const float* qr = F + PQ + (size_t)j*304;
      const float* qz = qr + 225*304;
      const float* qn = qr + 450*304;
      const float* w4r = F + PW4 + (size_t)j*456;
      float4 wr0 = ldg4(qr + k0), wz0 = ldg4(qz + k0), wn0 = ldg4(qn + k0);
      float4 w40 = ldg4(w4r + k0);
      float ar=0.f, az=0.f, ani=0.f, anh=0.f, a4=0.f;
      ar = dp4(ar, wr0, xq0); az = dp4(az, wz0, xq0);
      { float tt = dp4(0.f, wn0, xq0); if (k0 < 76) ani += tt; else anh += tt; }
      a4 = dp4(a4, w40, xw0);
      if (l < 12) {
        float4 wr1 = ldg4(qr + 256 + k0), wz1 = ldg4(qz + 256 + k0), wn1 = ldg4(qn + 256 + k0);
        ar = dp4(ar, wr1, xq1); az = dp4(az, wz1, xq1); anh = dp4(anh, wn1, xq1);
      }
      if (l < 50) a4 = dp4(a4, ldg4(w4r + 256 + k0), xw1);
      ar = red64(ar); az = red64(az); ani = red64(ani); anh = red64(anh); a4 = red64(a4);
      if (l == 0) {
        float r = sigf(ar + a.bihQ[j] + a.bhhQ[j]);
        float z = sigf(az + a.bihQ[225+j] + a.bhhQ[225+j]);
        float n = tanhf(ani + a.bihQ[450+j] + r*(anh + a.bhhQ[450+j]));
        ast(&hQo[bw*228 + j], (1.f - z)*n + z*ald(&hQi[bw*228 + j]));
        if (t > 0) ast(&F[F_HSIG + bw*228 + j], fmaxf(a4 + a.b4[j], 0.f));
      }
    }
    gbar(ib, ep); ++ep;

    // ==== B: out6(LDS) ; osig GRU (x=[hQ|out6], h=hSig) ====================
    if (bx < 225) {
      // FWD still in L_SCR from stage A
      for (int i = tid; i < 1200; i += NTH) {
        int bb = i/75, j6 = i - bb*75;
        const float4* w  = (const float4*)(F + PW6 + j6*16);
        const float4* xv = (const float4*)(smem + L_SCR + bb*16);
        float acc = a.b6[j6];
        acc = dp4(acc, w[0], xv[0]); acc = dp4(acc, w[1], xv[1]);
        acc = dp4(acc, w[2], xv[2]); acc = dp4(acc, w[3], xv[3]);
        smem[L_OUT6 + bb*76 + j6] = fmaxf(acc, 0.f);
      }
      __syncthreads();
      const int j = bx, bw = widx;
      float4 x0 = (l < 57) ? ald4(hQo + bw*228 + k0)
                           : *(const float4*)(smem + L_OUT6 + bw*76 + k0 - 228);
      float4 x1 = (l < 12) ? *(const float4*)(smem + L_OUT6 + bw*76 + 28 + k0)
                           : ald4(F + F_HSIG + bw*228 + k0 - 48);
      float4 x2; if (l < 5) x2 = ald4(F + F_HSIG + bw*228 + 208 + k0);
      const float* gr = F + PSIG + (size_t)j*544;
      const float* gz = gr + 225*544;
      const float* gn = gr + 450*544;
      float4 wr0 = ldg4(gr + k0),     wz0 = ldg4(gz + k0),     wn0 = ldg4(gn + k0);
      float4 wr1 = ldg4(gr + 256+k0), wz1 = ldg4(gz + 256+k0), wn1 = ldg4(gn + 256+k0);
      float ar=0.f, az=0.f, ani=0.f, anh=0.f;
      ar = dp4(ar, wr0, x0); az = dp4(az, wz0, x0); ani = dp4(ani, wn0, x0);
      ar = dp4(ar, wr1, x1); az = dp4(az, wz1, x1);
      { float tt = dp4(0.f, wn1, x1); if (l < 12) ani += tt; else anh += tt; }
      if (l < 5) {
        float4 wr2 = ldg4(gr + 512+k0), wz2 = ldg4(gz + 512+k0), wn2 = ldg4(gn + 512+k0);
        ar = dp4(ar, wr2, x2); az = dp4(az, wz2, x2); anh = dp4(anh, wn2, x2);
      }
      ar = red64(ar); az = red64(az); ani = red64(ani); anh = red64(anh);
      if (l == 0) {
        float r = sigf(ar + a.bihSig[j] + a.bhhSig[j]);
        float z = sigf(az + a.bihSig[225+j] + a.bhhSig[225+j]);
        float n = tanhf(ani + a.bihSig[450+j] + r*(anh + a.bhhSig[450+j]));
        float val = (1.f - z)*n + z*ald(&F[F_HSIG + bw*228 + j]);
        ast(&F[F_OSIG + bw*228 + j], val);
        ast(&F[F_XV + bw*452 + j], val);
      }
    }
    gbar(ib, ep); ++ep;

    // ==== C: out1 = relu(W1 @ osig + b1) ===================================
    if (bx < 225) {
      const int j = bx, bw = widx;
      float acc = 0.f;
      if (l < 57) {
        float4 w0 = ldg4(F + PW1 + (size_t)j*228 + k0);
        float4 x0 = ald4(F + F_OSIG + bw*228 + k0);
        acc = dp4(0.f, w0, x0);
      }
      acc = red64(acc);
      if (l == 0) ast(&F[F_OUT1 + bw*228 + j], fmaxf(acc + a.b1[j], 0.f));
    }
    gbar(ib, ep); ++ep;

    // ==== D: out7(LDS) ; hS GRU (x=[out1|out7], h=hS) ======================
    if (bx < 225) {
      if (tid < 256)      smem[L_SCR + tid]       = ald(F + F_OBSD + tid);
      else if (tid < 512) smem[L_SCR + tid]       = ald(F + F_DY + tid - 256);
      __syncthreads();
      for (int i = tid; i < 2400; i += NTH) {
        int bb = i/150, j7 = i - bb*150;
        const float4* w  = (const float4*)(F + PW7 + j7*32);
        const float4* vo = (const float4*)(smem + L_SCR + bb*16);
        const float4* vd = (const float4*)(smem + L_SCR + 256 + bb*16);
        float acc = a.b7[j7];
        acc = dp4(acc, w[0], vo[0]); acc = dp4(acc, w[1], vo[1]);
        acc = dp4(acc, w[2], vo[2]); acc = dp4(acc, w[3], vo[3]);
        acc = dp4(acc, w[4], vd[0]); acc = dp4(acc, w[5], vd[1]);
        acc = dp4(acc, w[6], vd[2]); acc = dp4(acc, w[7], vd[3]);
        smem[L_OUT7 + bb*152 + j7] = fmaxf(acc, 0.f);
      }
      __syncthreads();
      const int j = bx, bw = widx;
      float4 x0 = (l < 57) ? ald4(F + F_OUT1 + bw*228 + k0)
                           : *(const float4*)(smem + L_OUT7 + bw*152 + k0 - 228);
      float4 x1 = (l < 31) ? *(const float4*)(smem + L_OUT7 + bw*152 + 28 + k0)
                           : ald4(hSi + bw*228 + k0 - 124);
      float4 x2; if (l < 24) x2 = ald4(hSi + bw*228 + 132 + k0);
      const float* gr = F + PS + (size_t)j*608;
      const float* gz = gr + 225*608;
      const float* gn = gr + 450*608;
      float4 wr0 = ldg4(gr + k0),     wz0 = ldg4(gz + k0),     wn0 = ldg4(gn + k0);
      float4 wr1 = ldg4(gr + 256+k0), wz1 = ldg4(gz + 256+k0), wn1 = ldg4(gn + 256+k0);
      float ar=0.f, az=0.f, ani=0.f, anh=0.f;
      ar = dp4(ar, wr0, x0); az = dp4(az, wz0, x0); ani = dp4(ani, wn0, x0);
      ar = dp4(ar, wr1, x1); az = dp4(az, wz1, x1);
      { float tt = dp4(0.f, wn1, x1); if (l < 31) ani += tt; else anh += tt; }
      if (l < 24) {
        float4 wr2 = ldg4(gr + 512+k0), wz2 = ldg4(gz + 512+k0), wn2 = ldg4(gn + 512+k0);
        ar = dp4(ar, wr2, x2); az = dp4(az, wz2, x2); anh = dp4(anh, wn2, x2);
      }
      ar = red64(ar); az = red64(az); ani = red64(ani); anh = red64(anh);
      if (l == 0) {
        float r = sigf(ar + a.bihS[j] + a.bhhS[j]);
        float z = sigf(az + a.bihS[225+j] + a.bhhS[225+j]);
        float n = tanhf(ani + a.bihS[450+j] + r*(anh + a.bhhS[450+j]));
        float val = (1.f - z)*n + z*ald(&hSi[bw*228 + j]);
        ast(&hSo[bw*228 + j], val);
        ast(&F[F_XV + bw*452 + 225 + j], val);
      }
    }
    gbar(ib, ep); ++ep;

    // ==== E: hid2 = relu(W2aP @ xv + b2a) — 2 rows x 16 b per wave =========
    {
      for (int i = tid; i < 7232; i += NTH) smem[L_XV + i] = ald(F + F_XV + i);
      __syncthreads();
      if (bx < 250) {
        const int r0 = bx*72;
        for (int ps = 0; ps < 3; ++ps) {
          const int pi = ps*16 + widx;
          if (pi >= 36) break;
          const int rA = r0 + 2*pi;
          const float* wAp = F + W2AP + (size_t)rA*452;
          const float* wBp = wAp + 452;
          float aA[16], aB[16];
          #pragma unroll
          for (int i = 0; i < 16; ++i) { aA[i] = 0.f; aB[i] = 0.f; }
          {
            float4 wA = ldg4(wAp + k0), wB = ldg4(wBp + k0);
            #pragma unroll
            for (int bb = 0; bb < 16; ++bb) {
              float4 xv = *(const float4*)(smem + L_XV + bb*452 + k0);
              aA[bb] = dp4(aA[bb], wA, xv);
              aB[bb] = dp4(aB[bb], wB, xv);
            }
          }
          if (l < 49) {
            float4 wA = ldg4(wAp + 256 + k0), wB = ldg4(wBp + 256 + k0);
            #pragma unroll
            for (int bb = 0; bb < 16; ++bb) {
              float4 xv = *(const float4*)(smem + L_XV + bb*452 + 256 + k0);
              aA[bb] = dp4(aA[bb], wA, xv);
              aB[bb] = dp4(aB[bb], wB, xv);
            }
          }
          #pragma unroll
          for (int i = 0; i < 16; ++i) { aA[i] = red64(aA[i]); aB[i] = red64(aB[i]); }
          if (l == 0) {
            float bA = a.b2a[rA], bB = a.b2a[rA + 1];
            #pragma unroll
            for (int i = 0; i < 16; ++i) {
              ast(&F[F_HID2 + i*18000 + rA],     fmaxf(aA[i] + bA, 0.f));
              ast(&F[F_HID2 + i*18000 + rA + 1], fmaxf(aB[i] + bB, 0.f));
            }
          }
        }
      }
    }
    gbar(ib, ep); ++ep;

    // ==== F: W2b partials — 228 WGs: (jg=bx>>2, kq=bx&3), wave = b =========
    if (bx < 228) {
      const int jg = bx >> 2, kq = bx & 3, j0 = jg*4;
      const int nr = (jg == 56) ? 1 : 4;
      const float* hbf = F + F_HID2 + (size_t)widx*18000 + kq*4500;
      const float4* w0 = (const float4*)a.W2b + (size_t)j0*4500 + kq*1125;
      const float4* w1 = (nr > 1) ? ((const float4*)a.W2b + (size_t)(j0+1)*4500 + kq*1125) : w0;
      const float4* w2 = (nr > 1) ? ((const float4*)a.W2b + (size_t)(j0+2)*4500 + kq*1125) : w0;
      const float4* w3 = (nr > 1) ? ((const float4*)a.W2b + (size_t)(j0+3)*4500 + kq*1125) : w0;
      float a0=0.f, a1=0.f, a2=0.f, a3=0.f;
      #pragma unroll 2
      for (int c = 0; c < 17; ++c) {
        int idx = c*64 + l;
        float4 h4 = ald4(hbf + idx*4);
        float4 q0 = ldg4nt(w0+idx), q1 = ldg4nt(w1+idx), q2 = ldg4nt(w2+idx), q3 = ldg4nt(w3+idx);
        a0 = dp4(a0,q0,h4); a1 = dp4(a1,q1,h4); a2 = dp4(a2,q2,h4); a3 = dp4(a3,q3,h4);
      }
      if (l < 37) {
        int idx = 1088 + l;
        float4 h4 = ald4(hbf + idx*4);
        float4 q0 = ldg4nt(w0+idx), q1 = ldg4nt(w1+idx), q2 = ldg4nt(w2+idx), q3 = ldg4nt(w3+idx);
        a0 = dp4(a0,q0,h4); a1 = dp4(a1,q1,h4); a2 = dp4(a2,q2,h4); a3 = dp4(a3,q3,h4);
      }
      a0 = red64(a0); a1 = red64(a1); a2 = red64(a2); a3 = red64(a3);
      if (l == 0) {
        float* pp = F + F_P2 + ((widx*228 + j0) << 2) + kq;
        ast(pp, a0);
        if (nr > 1) { ast(pp+4, a1); ast(pp+8, a2); ast(pp+12, a3); }
      }
    }
    gbar(ib, ep); ++ep;

    // ==== G: out2(LDS) ; out3 = relu(W3@[hS|out2]+b3) ; x update ===========
    if (bx < 225) {
      for (int i = tid; i < 3648; i += NTH) {
        int bb = i/228, j2 = i - bb*228;
        float v = 0.f;
        if (j2 < 225) {
          float4 pq = ald4(F + F_P2 + ((bb*228 + j2) << 2));
          v = pq.x + pq.y + pq.z + pq.w + a.b2b[j2];
        }
        smem[L_OUT2 + i] = v;
      }
      __syncthreads();
      const int j = bx, bw = widx;
      float4 x0 = (l < 57) ? ald4(hSo + bw*228 + k0)
                           : *(const float4*)(smem + L_OUT2 + bw*228 + k0 - 228);
      float4 x1; if (l < 50) x1 = *(const float4*)(smem + L_OUT2 + bw*228 + 28 + k0);
      const float* w3r = F + PW3 + (size_t)j*456;
      float acc = dp4(0.f, ldg4(w3r + k0), x0);
      if (l < 50) acc = dp4(acc, ldg4(w3r + 256 + k0), x1);
      acc = red64(acc);
      if (l == 0) ast(&F[F_OUT3 + bw*228 + j], fmaxf(acc + a.b3[j], 0.f));
    } else if (bx == 225) {
      for (int i = tid; i < 240; i += NTH) {
        int bb = i/15, jj = i - bb*15;
        float4 pq = ald4(F + F_P2 + ((bb*228 + jj) << 2));
        float o2 = pq.x + pq.y + pq.z + pq.w + a.b2b[jj];
        float xold = ald(&F[F_XP + i]), dy = ald(&F[F_DY + bb*16 + jj]);
        float xnew = fmaf(o2, dy, xold);
        a.out[t*240 + i] = xnew;
        ast(&F[F_XP + i], xnew);
        if (t + 1 < TT) {
          float y1 = a.y[(t+1)*480 + bb*30 + jj];
          float y0 = a.y[t*480     + bb*30 + jj];
          ast(&F[F_DY   + bb*16 + jj], y1 - xnew);
          ast(&F[F_OBSD + bb*16 + jj], y1 - y0);
          ast(&F[F_FWD  + bb*16 + jj], xnew - xold);
        }
      }
    }
    gbar(ib, ep); ++ep;
  }
}

extern "C" void kernel_launch(void* const* d_in, const int* in_sizes, int n_in,
                              void* d_out, int out_size, void* d_ws, size_t ws_size,
                              hipStream_t stream) {
  (void)in_sizes; (void)n_in; (void)out_size; (void)ws_size;
  KArgs a;
  int k = 0;
  a.y      = (const float*)d_in[k++];
  a.x0     = (const float*)d_in[k++];
  a.hQ0    = (const float*)d_in[k++];
  a.hSig0  = (const float*)d_in[k++];
  a.hS0    = (const float*)d_in[k++];
  a.WihQ   = (const float*)d_in[k++];
  a.WhhQ   = (const float*)d_in[k++];
  a.bihQ   = (const float*)d_in[k++];
  a.bhhQ   = (const float*)d_in[k++];
  a.WihSig = (const float*)d_in[k++];
  a.WhhSig = (const float*)d_in[k++];
  a.bihSig = (const float*)d_in[k++];
  a.bhhSig = (const float*)d_in[k++];
  a.WihS   = (const float*)d_in[k++];
  a.WhhS   = (const float*)d_in[k++];
  a.bihS   = (const float*)d_in[k++];
  a.bhhS   = (const float*)d_in[k++];
  a.W1  = (const float*)d_in[k++];  a.b1  = (const float*)d_in[k++];
  a.W2a = (const float*)d_in[k++];  a.b2a = (const float*)d_in[k++];
  a.W2b = (const float*)d_in[k++];  a.b2b = (const float*)d_in[k++];
  a.W3  = (const float*)d_in[k++];  a.b3  = (const float*)d_in[k++];
  a.W4  = (const float*)d_in[k++];  a.b4  = (const float*)d_in[k++];
  a.W5  = (const float*)d_in[k++];  a.b5  = (const float*)d_in[k++];
  a.W6  = (const float*)d_in[k++];  a.b6  = (const float*)d_in[k++];
  a.W7  = (const float*)d_in[k++];  a.b7  = (const float*)d_in[k++];
  a.out = (float*)d_out;
  a.ib  = (int*)d_ws;
  a.fb  = (float*)((char*)d_ws + (size_t)INT_TOTAL*sizeof(int));

  hipLaunchKernelGGL(knet_init, dim3(2048), dim3(256), 0, stream, a);
  hipLaunchKernelGGL(knet_main, dim3(NWG), dim3(NTH), 0, stream, a);
}